// Round 2
// baseline (691.452 us; speedup 1.0000x reference)
//
#include <hip/hip_runtime.h>
#include <hip/hip_cooperative_groups.h>
#include <hip/hip_bf16.h>
#include <math.h>

namespace cg = cooperative_groups;

#define NN   30000
#define NE   300000
#define ETOT 330000   // NE + NN self loops
#define NB   300
#define EMB  64
#define D1   256      // 4 heads * 64
#define H1   4
#define H3   6
#define O3   121
#define D3   726      // 6 * 121
#define NQ   60       // 6 heads x 10 classes (pre-projected conv3 output)
#define N3   72       // NQ + 6 (es) + 6 (ed)
#define NCLS 10
#define CAP  64       // padded CSR slots per dst (max degree ~25 for this dataset)
#define LDA  40

typedef __attribute__((ext_vector_type(8))) short short8;
typedef __attribute__((ext_vector_type(8))) unsigned short ushort8;
typedef __attribute__((ext_vector_type(4))) float floatx4;

static inline int ceil_div(int a, int b) { return (a + b - 1) / b; }

__device__ inline void split_bf16(float f, unsigned short& hi, unsigned short& lo) {
    __hip_bfloat16 h = __float2bfloat16(f);
    float fh = __bfloat162float(h);
    __hip_bfloat16 l = __float2bfloat16(f - fh);
    hi = __builtin_bit_cast(unsigned short, h);
    lo = __builtin_bit_cast(unsigned short, l);
}

__device__ inline float bf2f(unsigned short u) {
    return __builtin_bit_cast(float, (unsigned int)u << 16);
}

__device__ inline unsigned short f2bf(float f) {
    return __builtin_bit_cast(unsigned short, __float2bfloat16(f));
}

__device__ inline float lrelu(float v) { return v > 0.f ? v : 0.2f * v; }

// ==================== device phase functions (shared by mega + fallback) ====================

// ---- phase 0a: zero cnt / G / gs / ge ----
__device__ __forceinline__ void phase_zero(int* __restrict__ cnt, float* __restrict__ G,
                                           int* __restrict__ gs, int* __restrict__ ge) {
    int base = blockIdx.x * blockDim.x + threadIdx.x;
    int stride = gridDim.x * blockDim.x;
    const int TOT = NN + NB * NCLS + 2 * NB;
    for (int i = base; i < TOT; i += stride) {
        if (i < NN) cnt[i] = 0;
        else if (i < NN + NB * NCLS) G[i - NN] = 0.f;
        else if (i < NN + NB * NCLS + NB) gs[i - NN - NB * NCLS] = 0;
        else ge[i - NN - NB * NCLS - NB] = 0;
    }
}

// ---- phase 0b: node encode + CSR fill + ranges + weight prep ----
__device__ __forceinline__ void phase_setup(
    const int* __restrict__ x, const int* __restrict__ dep,
    const int* __restrict__ ei, const int* __restrict__ batch,
    const float* __restrict__ nemb, const float* __restrict__ demb,
    const float* __restrict__ w1, const float* __restrict__ w2,
    const float* __restrict__ w3, const float* __restrict__ as3,
    const float* __restrict__ ad3, const float* __restrict__ wp,
    unsigned short* __restrict__ H0hi, unsigned short* __restrict__ H0lo,
    unsigned short* __restrict__ W1hi, unsigned short* __restrict__ W1lo,
    unsigned short* __restrict__ W2b, unsigned short* __restrict__ W3b,
    int* __restrict__ cnt, int* __restrict__ csr,
    int* __restrict__ gs, int* __restrict__ ge) {
    int base = blockIdx.x * blockDim.x + threadIdx.x;
    int stride = gridDim.x * blockDim.x;   // multiple of 64 -> 8-lane shfl groups stay aligned
    for (int i = base; i < NN * EMB; i += stride) {
        {
            int n = i >> 6, d = i & 63;
            float v = nemb[x[n] * EMB + d] + demb[dep[n] * EMB + d];
            split_bf16(v, H0hi[i], H0lo[i]);
        }
        if (i < ETOT) {
            int src, dst;
            if (i < NE) { src = ei[i]; dst = ei[NE + i]; }
            else        { src = i - NE; dst = src; }
            int slot = atomicAdd(&cnt[dst], 1);
            csr[dst * CAP + slot] = src;
        }
        if (i < NN) {
            int b = batch[i];
            if (i == 0 || batch[i - 1] != b) gs[b] = i;
            if (i == NN - 1 || batch[i + 1] != b) ge[b] = i + 1;
        }
        if (i < EMB * D1) {
            int k = i / D1, n = i % D1;
            unsigned short h, l;
            split_bf16(w1[i], h, l);
            W1hi[n * EMB + k] = h;
            W1lo[n * EMB + k] = l;
        }
        if (i < D1 * D1) {
            int k = i / D1, n = i % D1;
            W2b[n * D1 + k] = f2bf(w2[i]);
        }
        if (i < N3 * D1 * 8) {   // 147456, multiple of 8 -> full shfl groups
            int oid = i >> 3, sub = i & 7;
            int n = oid / D1, k = oid % D1;
            const float* wrow = w3 + (size_t)k * D3;
            float acc = 0.f;
            if (n < NQ) {
                int h = n / NCLS, c = n % NCLS;
                const float* wr = wrow + h * O3;
                for (int j = sub; j < O3; j += 8) acc += wr[j] * wp[j * NCLS + c];
            } else if (n < NQ + H3) {
                int h = n - NQ;
                const float* wr = wrow + h * O3;
                for (int j = sub; j < O3; j += 8) acc += wr[j] * as3[h * O3 + j];
            } else {
                int h = n - NQ - H3;
                const float* wr = wrow + h * O3;
                for (int j = sub; j < O3; j += 8) acc += wr[j] * ad3[h * O3 + j];
            }
            acc += __shfl_xor(acc, 1);
            acc += __shfl_xor(acc, 2);
            acc += __shfl_xor(acc, 4);
            if (sub == 0) W3b[oid] = f2bf(acc);
        }
    }
}

// ---- GEMM phase: C[MxN] = A[MxK] * BT[NxK]^T, grid-stride over 128x128 tiles ----
// SPLIT=true : split-bf16 A and B (3 MFMA per frag) — conv1 only.
// MODE 0: bf16 P out (N=256) + fused es/ed logits epilogue.
// MODE 1: bf16 Q[.,60] + fp32 es[.,6] + ed[.,6] (conv3 pre-folded B).
template <int MODE, bool SPLIT>
__device__ __forceinline__ void gemm_phase(
    unsigned short* __restrict__ sAh, unsigned short* __restrict__ sAl,
    unsigned short* __restrict__ sBh, unsigned short* __restrict__ sBl,
    const unsigned short* __restrict__ Ahi, const unsigned short* __restrict__ Alo,
    const unsigned short* __restrict__ Bhi, const unsigned short* __restrict__ Blo,
    unsigned short* __restrict__ Cbf, unsigned short* __restrict__ Qb,
    float* __restrict__ es, float* __restrict__ ed,
    const float* __restrict__ as_, const float* __restrict__ ad_,
    int M, int K, int N, int nbx) {
    int tid = threadIdx.x;
    int lane = tid & 63, wave = tid >> 6;
    int wr = (wave >> 1) * 64, wc = (wave & 1) * 64;
    int quad = lane >> 4, mr = lane & 15;
    int nby = (M + 127) >> 7;
    int ntiles = nbx * nby;

    for (int tile = blockIdx.x; tile < ntiles; tile += gridDim.x) {
        int row0 = (tile / nbx) * 128, col0 = (tile % nbx) * 128;

        floatx4 zero = {0.f, 0.f, 0.f, 0.f};
        floatx4 acc[4][4];
        #pragma unroll
        for (int i = 0; i < 4; i++)
            #pragma unroll
            for (int j = 0; j < 4; j++) acc[i][j] = zero;

        for (int k0 = 0; k0 < K; k0 += 32) {
            #pragma unroll
            for (int ch = 0; ch < 2; ch++) {
                int linear = (ch * 256 + tid) * 8;   // 128*32 = 4096 elements
                int r = linear >> 5, c = linear & 31;
                uint4 vh, vl;
                int gr = row0 + r;
                if (gr < M) {
                    vh = *(const uint4*)(Ahi + (size_t)gr * K + k0 + c);
                    if (SPLIT) vl = *(const uint4*)(Alo + (size_t)gr * K + k0 + c);
                } else { vh = uint4{0, 0, 0, 0}; vl = uint4{0, 0, 0, 0}; }
                *(uint4*)&sAh[r * LDA + c] = vh;
                if (SPLIT) *(uint4*)&sAl[r * LDA + c] = vl;
                int gn = col0 + r;
                if (gn < N) {
                    vh = *(const uint4*)(Bhi + (size_t)gn * K + k0 + c);
                    if (SPLIT) vl = *(const uint4*)(Blo + (size_t)gn * K + k0 + c);
                } else { vh = uint4{0, 0, 0, 0}; vl = uint4{0, 0, 0, 0}; }
                *(uint4*)&sBh[r * LDA + c] = vh;
                if (SPLIT) *(uint4*)&sBl[r * LDA + c] = vl;
            }
            __syncthreads();

            short8 ah[4], al[4], bh[4], bl[4];
            #pragma unroll
            for (int i = 0; i < 4; i++) {
                int ar = wr + i * 16 + mr;
                ah[i] = *(const short8*)&sAh[ar * LDA + quad * 8];
                if (SPLIT) al[i] = *(const short8*)&sAl[ar * LDA + quad * 8];
                int br = wc + i * 16 + mr;
                bh[i] = *(const short8*)&sBh[br * LDA + quad * 8];
                if (SPLIT) bl[i] = *(const short8*)&sBl[br * LDA + quad * 8];
            }
            #pragma unroll
            for (int i = 0; i < 4; i++)
                #pragma unroll
                for (int j = 0; j < 4; j++) {
                    acc[i][j] = __builtin_amdgcn_mfma_f32_16x16x32_bf16(ah[i], bh[j], acc[i][j], 0, 0, 0);
                    if (SPLIT) {
                        acc[i][j] = __builtin_amdgcn_mfma_f32_16x16x32_bf16(ah[i], bl[j], acc[i][j], 0, 0, 0);
                        acc[i][j] = __builtin_amdgcn_mfma_f32_16x16x32_bf16(al[i], bh[j], acc[i][j], 0, 0, 0);
                    }
                }
            __syncthreads();
        }

        #pragma unroll
        for (int i = 0; i < 4; i++) {
            #pragma unroll
            for (int j = 0; j < 4; j++) {
                int gc = col0 + wc + j * 16 + mr;
                if (gc >= N) continue;
                int gr0 = row0 + wr + i * 16 + quad * 4;
                #pragma unroll
                for (int r = 0; r < 4; r++) {
                    int gr = gr0 + r;
                    if (gr >= M) continue;
                    float v = acc[i][j][r];
                    if (MODE == 0) {
                        Cbf[(size_t)gr * D1 + gc] = f2bf(v);
                    } else {
                        if (gc < NQ)            Qb[(size_t)gr * NQ + gc] = f2bf(v);
                        else if (gc < NQ + H3)  es[(size_t)gr * H3 + (gc - NQ)] = v;
                        else                    ed[(size_t)gr * H3 + (gc - NQ - H3)] = v;
                    }
                }
            }
        }

        if (MODE == 0) {
            // fused logits: this wave owns head hx for rows wr..wr+63
            int hx = 2 * (tile % nbx) + (wave & 1);
            float asr[4], adr[4];
            #pragma unroll
            for (int j = 0; j < 4; j++) {
                asr[j] = as_[hx * 64 + j * 16 + mr];
                adr[j] = ad_[hx * 64 + j * 16 + mr];
            }
            #pragma unroll
            for (int i = 0; i < 4; i++) {
                #pragma unroll
                for (int r = 0; r < 4; r++) {
                    float ps = 0.f, pd = 0.f;
                    #pragma unroll
                    for (int j = 0; j < 4; j++) {
                        float v = acc[i][j][r];
                        ps += v * asr[j];
                        pd += v * adr[j];
                    }
                    #pragma unroll
                    for (int m2 = 8; m2 >= 1; m2 >>= 1) {
                        ps += __shfl_xor(ps, m2);
                        pd += __shfl_xor(pd, m2);
                    }
                    int gr = row0 + wr + i * 16 + quad * 4 + r;
                    if (mr == 0 && gr < M) {
                        es[gr * 4 + hx] = ps;
                        ed[gr * 4 + hx] = pd;
                    }
                }
            }
        }
    }
}

// ---- conv1/2 aggregation: half-wave per edge, 8 features per lane ----
__device__ __forceinline__ void agg12_phase(
    const unsigned short* __restrict__ P, const float* __restrict__ es,
    const float* __restrict__ ed, const int* __restrict__ cnt,
    const int* __restrict__ csr, const float* __restrict__ bias,
    unsigned short* __restrict__ outHi) {
    int wave = threadIdx.x >> 6, lane = threadIdx.x & 63;
    int hi = lane >> 5;            // which edge of the pair
    int fl = lane & 31;            // feature-lane: features fl*8 .. fl*8+7
    int hq = fl >> 3;              // head of those features
    int f0 = fl * 8;
    float bv[8];
    #pragma unroll
    for (int j = 0; j < 8; j++) bv[j] = bias[f0 + j];
    for (int dst = blockIdx.x * 4 + wave; dst < NN; dst += gridDim.x * 4) {
        int s0 = dst * CAP, s1 = s0 + cnt[dst];
        float edv = ed[dst * 4 + hq];
        float sum = 0.f;
        float acc[8];
        #pragma unroll
        for (int j = 0; j < 8; j++) acc[j] = 0.f;
        int s = s0;
        for (; s + 8 <= s1; s += 8) {      // 4 pairs = 8 edges
            int si[4]; float ev[4]; ushort8 pp[4];
            #pragma unroll
            for (int u = 0; u < 4; u++) si[u] = csr[s + 2 * u + hi];
            #pragma unroll
            for (int u = 0; u < 4; u++) {
                ev[u] = es[si[u] * 4 + hq] + edv;
                pp[u] = *(const ushort8*)(P + (size_t)si[u] * D1 + f0);
            }
            #pragma unroll
            for (int u = 0; u < 4; u++) {
                float e = __expf(lrelu(ev[u]));
                sum += e;
                #pragma unroll
                for (int j = 0; j < 8; j++) acc[j] += e * bf2f(pp[u][j]);
            }
        }
        for (; s + 4 <= s1; s += 4) {      // 2 pairs = 4 edges
            int si[2]; float ev[2]; ushort8 pp[2];
            #pragma unroll
            for (int u = 0; u < 2; u++) si[u] = csr[s + 2 * u + hi];
            #pragma unroll
            for (int u = 0; u < 2; u++) {
                ev[u] = es[si[u] * 4 + hq] + edv;
                pp[u] = *(const ushort8*)(P + (size_t)si[u] * D1 + f0);
            }
            #pragma unroll
            for (int u = 0; u < 2; u++) {
                float e = __expf(lrelu(ev[u]));
                sum += e;
                #pragma unroll
                for (int j = 0; j < 8; j++) acc[j] += e * bf2f(pp[u][j]);
            }
        }
        for (; s < s1; s += 2) {           // masked final pair (1-2 edges)
            int idx = s + hi;
            bool v = idx < s1;
            int si = csr[v ? idx : s];
            float evv = es[si * 4 + hq] + edv;
            ushort8 p8 = *(const ushort8*)(P + (size_t)si * D1 + f0);
            float e = v ? __expf(lrelu(evv)) : 0.f;
            sum += e;
            #pragma unroll
            for (int j = 0; j < 8; j++) acc[j] += e * bf2f(p8[j]);
        }
        sum += __shfl_xor(sum, 32);
        #pragma unroll
        for (int j = 0; j < 8; j++) acc[j] += __shfl_xor(acc[j], 32);
        float inv = 1.f / sum;
        if (lane < 32) {
            ushort8 o8;
            #pragma unroll
            for (int j = 0; j < 8; j++) {
                float a = acc[j] * inv + bv[j];
                a = a > 0.f ? a : expm1f(a);
                o8[j] = f2bf(a);
            }
            *(ushort8*)(outHi + (size_t)dst * D1 + f0) = o8;
        }
    }
}

// ---- conv3 aggregation: one-pass softmax + bf16 Q-gather + pool/classify ----
__device__ __forceinline__ void agg3q_phase(
    const unsigned short* __restrict__ Qb, const float* __restrict__ es,
    const float* __restrict__ ed, const int* __restrict__ cnt,
    const int* __restrict__ csr, const int* __restrict__ batch,
    float* __restrict__ G) {
    int wave = threadIdx.x >> 6, lane = threadIdx.x & 63;
    bool act = lane < NQ;
    int h = act ? (lane / NCLS) : 0;
    int q = act ? lane : 0;
    for (int dst = blockIdx.x * 4 + wave; dst < NN; dst += gridDim.x * 4) {
        int b = batch[dst];
        int s0 = dst * CAP, s1 = s0 + cnt[dst];
        float edv = act ? ed[dst * H3 + h] : 0.f;
        float sum = 0.f, acc = 0.f;
        int s = s0;
        for (; s + 8 <= s1; s += 8) {
            int si[8];
            #pragma unroll
            for (int u = 0; u < 8; u++) si[u] = csr[s + u];
            float vv[8], qq[8];
            #pragma unroll
            for (int u = 0; u < 8; u++) {
                vv[u] = es[si[u] * H3 + h] + edv;
                qq[u] = bf2f(Qb[(size_t)si[u] * NQ + q]);
            }
            #pragma unroll
            for (int u = 0; u < 8; u++) {
                float e = __expf(lrelu(vv[u]));
                sum += e;
                acc += e * qq[u];
            }
        }
        for (; s + 2 <= s1; s += 2) {
            int sa = csr[s], sb = csr[s + 1];
            float va = es[sa * H3 + h] + edv;
            float vb = es[sb * H3 + h] + edv;
            float qa = bf2f(Qb[(size_t)sa * NQ + q]);
            float qb = bf2f(Qb[(size_t)sb * NQ + q]);
            float ea = __expf(lrelu(va));
            float eb = __expf(lrelu(vb));
            sum += ea + eb;
            acc += ea * qa + eb * qb;
        }
        for (; s < s1; s++) {
            int sa = csr[s];
            float va = es[sa * H3 + h] + edv;
            float qa = bf2f(Qb[(size_t)sa * NQ + q]);
            float ea = __expf(lrelu(va));
            sum += ea;
            acc += ea * qa;
        }
        acc *= 1.f / sum;
        float av = act ? acc : 0.f;
        float tot = av;
        #pragma unroll
        for (int h2 = 1; h2 < H3; h2++) tot += __shfl(av, lane + h2 * NCLS);
        if (lane < NCLS) atomicAdd(&G[b * NCLS + lane], tot);
    }
}

// ---- final: per-graph mean + folded b3 bias + bp (one wave per graph) ----
__device__ __forceinline__ void final_phase(
    const float* __restrict__ G, const int* __restrict__ gs, const int* __restrict__ ge,
    const float* __restrict__ b3, const float* __restrict__ wp,
    const float* __restrict__ bp, float* __restrict__ out) {
    int wave = threadIdx.x >> 6, lane = threadIdx.x & 63;
    for (int b = blockIdx.x * 4 + wave; b < NB; b += gridDim.x * 4) {
        if (lane < NCLS) {
            int cntn = ge[b] - gs[b];
            float o = bp[lane];
            if (cntn > 0) {
                float bt = 0.f;
                for (int k = 0; k < O3; k++) {
                    float bs = 0.f;
                    #pragma unroll
                    for (int hh = 0; hh < H3; hh++) bs += b3[hh * O3 + k];
                    bt += bs * wp[k * NCLS + lane];
                }
                o += G[b * NCLS + lane] / (6.f * (float)cntn) + bt * (1.f / 6.f);
            }
            out[b * NCLS + lane] = o;
        }
    }
}

// ==================== persistent cooperative mega-kernel ====================

struct MegaArgs {
    const int *x, *dep, *ei, *batch;
    const float *nemb, *demb, *w1, *as1, *ad1, *b1, *w2, *as2, *ad2, *b2;
    const float *w3, *as3, *ad3, *b3, *wp, *bp;
    float* out;
    unsigned short *Hb, *H0lo, *W1hi, *W1lo, *W2b, *W3b, *Pb, *Qb;
    float *G, *es, *ed;
    int *cnt, *csr, *gs, *ge;
};

__global__ __launch_bounds__(256, 2) void mega_kernel(MegaArgs a) {
    __shared__ unsigned short sAh[128 * LDA], sBh[128 * LDA];
    __shared__ unsigned short sAl[128 * LDA], sBl[128 * LDA];
    cg::grid_group grid = cg::this_grid();

    phase_zero(a.cnt, a.G, a.gs, a.ge);
    grid.sync();

    phase_setup(a.x, a.dep, a.ei, a.batch, a.nemb, a.demb, a.w1, a.w2, a.w3,
                a.as3, a.ad3, a.wp, a.Hb, a.H0lo, a.W1hi, a.W1lo, a.W2b, a.W3b,
                a.cnt, a.csr, a.gs, a.ge);
    grid.sync();

    gemm_phase<0, true>(sAh, sAl, sBh, sBl, a.Hb, a.H0lo, a.W1hi, a.W1lo,
                        a.Pb, nullptr, a.es, a.ed, a.as1, a.ad1, NN, EMB, D1, 2);
    grid.sync();

    agg12_phase(a.Pb, a.es, a.ed, a.cnt, a.csr, a.b1, a.Hb);
    grid.sync();

    gemm_phase<0, false>(sAh, sAl, sBh, sBl, a.Hb, nullptr, a.W2b, nullptr,
                         a.Pb, nullptr, a.es, a.ed, a.as2, a.ad2, NN, D1, D1, 2);
    grid.sync();

    agg12_phase(a.Pb, a.es, a.ed, a.cnt, a.csr, a.b2, a.Hb);
    grid.sync();

    gemm_phase<1, false>(sAh, sAl, sBh, sBl, a.Hb, nullptr, a.W3b, nullptr,
                         nullptr, a.Qb, a.es, a.ed, nullptr, nullptr, NN, D1, N3, 1);
    grid.sync();

    agg3q_phase(a.Qb, a.es, a.ed, a.cnt, a.csr, a.batch, a.G);
    grid.sync();

    final_phase(a.G, a.gs, a.ge, a.b3, a.wp, a.bp, a.out);
}

// ==================== fallback (non-cooperative) wrappers ====================

__global__ void fb_zero_kernel(int* cnt, float* G, int* gs, int* ge) {
    phase_zero(cnt, G, gs, ge);
}

__global__ void fb_setup_kernel(const int* x, const int* dep, const int* ei, const int* batch,
                                const float* nemb, const float* demb, const float* w1,
                                const float* w2, const float* w3, const float* as3,
                                const float* ad3, const float* wp,
                                unsigned short* H0hi, unsigned short* H0lo,
                                unsigned short* W1hi, unsigned short* W1lo,
                                unsigned short* W2b, unsigned short* W3b,
                                int* cnt, int* csr, int* gs, int* ge) {
    phase_setup(x, dep, ei, batch, nemb, demb, w1, w2, w3, as3, ad3, wp,
                H0hi, H0lo, W1hi, W1lo, W2b, W3b, cnt, csr, gs, ge);
}

template <int MODE, bool SPLIT>
__global__ __launch_bounds__(256) void fb_gemm_kernel(
    const unsigned short* Ahi, const unsigned short* Alo,
    const unsigned short* Bhi, const unsigned short* Blo,
    unsigned short* Cbf, unsigned short* Qb, float* es, float* ed,
    const float* as_, const float* ad_, int M, int K, int N, int nbx) {
    __shared__ unsigned short sAh[128 * LDA], sBh[128 * LDA];
    __shared__ unsigned short sAl[SPLIT ? 128 * LDA : 1], sBl[SPLIT ? 128 * LDA : 1];
    gemm_phase<MODE, SPLIT>(sAh, sAl, sBh, sBl, Ahi, Alo, Bhi, Blo,
                            Cbf, Qb, es, ed, as_, ad_, M, K, N, nbx);
}

__global__ __launch_bounds__(256) void fb_agg12_kernel(
    const unsigned short* P, const float* es, const float* ed, const int* cnt,
    const int* csr, const float* bias, unsigned short* outHi) {
    agg12_phase(P, es, ed, cnt, csr, bias, outHi);
}

__global__ __launch_bounds__(256) void fb_agg3q_kernel(
    const unsigned short* Qb, const float* es, const float* ed, const int* cnt,
    const int* csr, const int* batch, float* G) {
    agg3q_phase(Qb, es, ed, cnt, csr, batch, G);
}

__global__ __launch_bounds__(256) void fb_final_kernel(
    const float* G, const int* gs, const int* ge, const float* b3,
    const float* wp, const float* bp, float* out) {
    final_phase(G, gs, ge, b3, wp, bp, out);
}

// ==================== launch ====================

extern "C" void kernel_launch(void* const* d_in, const int* in_sizes, int n_in,
                              void* d_out, int out_size, void* d_ws, size_t ws_size,
                              hipStream_t stream) {
    MegaArgs a;
    a.x     = (const int*)d_in[0];
    a.dep   = (const int*)d_in[1];
    a.ei    = (const int*)d_in[2];
    a.batch = (const int*)d_in[3];
    a.nemb  = (const float*)d_in[4];
    a.demb  = (const float*)d_in[5];
    a.w1    = (const float*)d_in[6];
    a.as1   = (const float*)d_in[7];
    a.ad1   = (const float*)d_in[8];
    a.b1    = (const float*)d_in[9];
    a.w2    = (const float*)d_in[10];
    a.as2   = (const float*)d_in[11];
    a.ad2   = (const float*)d_in[12];
    a.b2    = (const float*)d_in[13];
    a.w3    = (const float*)d_in[14];
    a.as3   = (const float*)d_in[15];
    a.ad3   = (const float*)d_in[16];
    a.b3    = (const float*)d_in[17];
    a.wp    = (const float*)d_in[18];
    a.bp    = (const float*)d_in[19];
    a.out   = (float*)d_out;

    char* ws = (char*)d_ws;
    size_t off = 0;
    auto alloc = [&](size_t bytes) -> void* {
        void* p = ws + off;
        off += (bytes + 255) & ~(size_t)255;
        return p;
    };
    a.Hb   = (unsigned short*)alloc((size_t)NN * D1 * 2);     // H0 (stride 64) then H1/H2 (stride 256)
    a.H0lo = (unsigned short*)alloc((size_t)NN * EMB * 2);
    a.W1hi = (unsigned short*)alloc((size_t)D1 * EMB * 2);
    a.W1lo = (unsigned short*)alloc((size_t)D1 * EMB * 2);
    a.W2b  = (unsigned short*)alloc((size_t)D1 * D1 * 2);
    a.W3b  = (unsigned short*)alloc((size_t)N3 * D1 * 2);
    a.Pb   = (unsigned short*)alloc((size_t)NN * D1 * 2);
    a.Qb   = (unsigned short*)alloc(((size_t)NN * NQ + 64) * 2);
    a.G    = (float*)alloc((size_t)NB * NCLS * 4);
    a.es   = (float*)alloc((size_t)NN * 6 * 4);
    a.ed   = (float*)alloc((size_t)NN * 6 * 4);
    a.cnt  = (int*)alloc((size_t)NN * 4);
    a.csr  = (int*)alloc((size_t)NN * CAP * 4);
    a.gs   = (int*)alloc((size_t)NB * 4);
    a.ge   = (int*)alloc((size_t)NB * 4);

    // size the cooperative grid once (host-side queries only; capture-safe)
    static int s_grid = 0;
    if (s_grid == 0) {
        int dev = 0;
        (void)hipGetDevice(&dev);
        int cus = 0;
        if (hipDeviceGetAttribute(&cus, hipDeviceAttributeMultiprocessorCount, dev) != hipSuccess || cus <= 0)
            cus = 256;
        int occ = 0;
        if (hipOccupancyMaxActiveBlocksPerMultiprocessor(&occ, (const void*)mega_kernel, 256, 0) != hipSuccess || occ <= 0)
            occ = 2;
        long long g = (long long)cus * occ;
        if (g > 1024) g = 1024;
        s_grid = (int)g;
    }

    void* kargs[] = { (void*)&a };
    hipError_t e = hipLaunchCooperativeKernel((const void*)mega_kernel,
                                              dim3(s_grid), dim3(256), kargs, 0, stream);
    if (e != hipSuccess) {
        // fallback: 10-launch non-cooperative pipeline (identical phase code)
        fb_zero_kernel<<<ceil_div(NN + NB * NCLS + 2 * NB, 256), 256, 0, stream>>>(
            a.cnt, a.G, a.gs, a.ge);
        fb_setup_kernel<<<ceil_div(NN * EMB, 256), 256, 0, stream>>>(
            a.x, a.dep, a.ei, a.batch, a.nemb, a.demb, a.w1, a.w2, a.w3, a.as3, a.ad3, a.wp,
            a.Hb, a.H0lo, a.W1hi, a.W1lo, a.W2b, a.W3b, a.cnt, a.csr, a.gs, a.ge);
        fb_gemm_kernel<0, true><<<2 * ceil_div(NN, 128), 256, 0, stream>>>(
            a.Hb, a.H0lo, a.W1hi, a.W1lo, a.Pb, nullptr, a.es, a.ed, a.as1, a.ad1,
            NN, EMB, D1, 2);
        fb_agg12_kernel<<<NN / 16, 256, 0, stream>>>(a.Pb, a.es, a.ed, a.cnt, a.csr, a.b1, a.Hb);
        fb_gemm_kernel<0, false><<<2 * ceil_div(NN, 128), 256, 0, stream>>>(
            a.Hb, nullptr, a.W2b, nullptr, a.Pb, nullptr, a.es, a.ed, a.as2, a.ad2,
            NN, D1, D1, 2);
        fb_agg12_kernel<<<NN / 16, 256, 0, stream>>>(a.Pb, a.es, a.ed, a.cnt, a.csr, a.b2, a.Hb);
        fb_gemm_kernel<1, false><<<ceil_div(NN, 128), 256, 0, stream>>>(
            a.Hb, nullptr, a.W3b, nullptr, nullptr, a.Qb, a.es, a.ed, nullptr, nullptr,
            NN, D1, N3, 1);
        fb_agg3q_kernel<<<NN / 16, 256, 0, stream>>>(a.Qb, a.es, a.ed, a.cnt, a.csr, a.batch, a.G);
        fb_final_kernel<<<ceil_div(NB, 4), 256, 0, stream>>>(a.G, a.gs, a.ge, a.b3, a.wp, a.bp, a.out);
    }
}

// Round 3
// 555.478 us; speedup vs baseline: 1.2448x; 1.2448x over previous
//
#include <hip/hip_runtime.h>
#include <hip/hip_bf16.h>
#include <math.h>

#define NN   30000
#define NE   300000
#define ETOT 330000   // NE + NN self loops
#define NB   300
#define EMB  64
#define D1   256      // 4 heads * 64
#define H1   4
#define H3   6
#define O3   121
#define D3   726      // 6 * 121
#define NQ   60       // 6 heads x 10 classes (pre-projected conv3 output)
#define N3   72       // NQ + 6 (es) + 6 (ed)
#define NCLS 10
#define CAP  64       // padded CSR slots per dst (max degree ~25 for this dataset)
#define LDA  40

typedef __attribute__((ext_vector_type(8))) short short8;
typedef __attribute__((ext_vector_type(8))) unsigned short ushort8;
typedef __attribute__((ext_vector_type(4))) float floatx4;

static inline int ceil_div(int a, int b) { return (a + b - 1) / b; }

__device__ inline void split_bf16(float f, unsigned short& hi, unsigned short& lo) {
    __hip_bfloat16 h = __float2bfloat16(f);
    float fh = __bfloat162float(h);
    __hip_bfloat16 l = __float2bfloat16(f - fh);
    hi = __builtin_bit_cast(unsigned short, h);
    lo = __builtin_bit_cast(unsigned short, l);
}

__device__ inline float bf2f(unsigned short u) {
    return __builtin_bit_cast(float, (unsigned int)u << 16);
}

__device__ inline unsigned short f2bf(float f) {
    return __builtin_bit_cast(unsigned short, __float2bfloat16(f));
}

__device__ inline float lrelu(float v) { return v > 0.f ? v : 0.2f * v; }

// ---- lightweight XCD-safe grid barrier -------------------------------------
// Per-phase dedicated counter (no reset logic). Release: threadfence (L2 wb) +
// device-scope atomicAdd. Wait: thread0-only RELAXED agent atomic load (coherent,
// NO per-poll cache invalidation - this is what makes it fast vs cg::grid.sync)
// with s_sleep backoff; one acquire fence (L2 inv) after the spin.
__device__ __forceinline__ void gbar(int* __restrict__ bar, int idx) {
    __syncthreads();
    if (threadIdx.x == 0) {
        __threadfence();
        atomicAdd(&bar[idx * 32], 1);
        int nb = (int)gridDim.x;
        while (__hip_atomic_load(&bar[idx * 32], __ATOMIC_RELAXED,
                                 __HIP_MEMORY_SCOPE_AGENT) < nb) {
            __builtin_amdgcn_s_sleep(16);
        }
        __threadfence();
    }
    __syncthreads();
}

// ==================== device phase functions ====================

// ---- setup: node encode + CSR fill + ranges + weight prep + btv ----
// (cnt/G/gs/ge/bar are zeroed by a pre-launch hipMemsetAsync)
__device__ __forceinline__ void phase_setup(
    const int* __restrict__ x, const int* __restrict__ dep,
    const int* __restrict__ ei, const int* __restrict__ batch,
    const float* __restrict__ nemb, const float* __restrict__ demb,
    const float* __restrict__ w1, const float* __restrict__ w2,
    const float* __restrict__ w3, const float* __restrict__ as3,
    const float* __restrict__ ad3, const float* __restrict__ wp,
    const float* __restrict__ b3,
    unsigned short* __restrict__ H0hi, unsigned short* __restrict__ H0lo,
    unsigned short* __restrict__ W1hi, unsigned short* __restrict__ W1lo,
    unsigned short* __restrict__ W2b, unsigned short* __restrict__ W3b,
    float* __restrict__ btv,
    int* __restrict__ cnt, int* __restrict__ csr,
    int* __restrict__ gs, int* __restrict__ ge) {
    int base = blockIdx.x * blockDim.x + threadIdx.x;
    int stride = gridDim.x * blockDim.x;   // multiple of 64 -> 8-lane shfl groups stay aligned
    for (int i = base; i < NN * EMB; i += stride) {
        {
            int n = i >> 6, d = i & 63;
            float v = nemb[x[n] * EMB + d] + demb[dep[n] * EMB + d];
            split_bf16(v, H0hi[i], H0lo[i]);
        }
        if (i < ETOT) {
            int src, dst;
            if (i < NE) { src = ei[i]; dst = ei[NE + i]; }
            else        { src = i - NE; dst = src; }
            int slot = atomicAdd(&cnt[dst], 1);
            csr[dst * CAP + slot] = src;
        }
        if (i < NN) {
            int b = batch[i];
            if (i == 0 || batch[i - 1] != b) gs[b] = i;
            if (i == NN - 1 || batch[i + 1] != b) ge[b] = i + 1;
        }
        if (i < EMB * D1) {
            int k = i / D1, n = i % D1;
            unsigned short h, l;
            split_bf16(w1[i], h, l);
            W1hi[n * EMB + k] = h;
            W1lo[n * EMB + k] = l;
        }
        if (i < D1 * D1) {
            int k = i / D1, n = i % D1;
            W2b[n * D1 + k] = f2bf(w2[i]);
        }
        if (i < N3 * D1 * 8) {   // 147456, multiple of 8 -> full shfl groups
            int oid = i >> 3, sub = i & 7;
            int n = oid / D1, k = oid % D1;
            const float* wrow = w3 + (size_t)k * D3;
            float acc = 0.f;
            if (n < NQ) {
                int h = n / NCLS, c = n % NCLS;
                const float* wr = wrow + h * O3;
                for (int j = sub; j < O3; j += 8) acc += wr[j] * wp[j * NCLS + c];
            } else if (n < NQ + H3) {
                int h = n - NQ;
                const float* wr = wrow + h * O3;
                for (int j = sub; j < O3; j += 8) acc += wr[j] * as3[h * O3 + j];
            } else {
                int h = n - NQ - H3;
                const float* wr = wrow + h * O3;
                for (int j = sub; j < O3; j += 8) acc += wr[j] * ad3[h * O3 + j];
            }
            acc += __shfl_xor(acc, 1);
            acc += __shfl_xor(acc, 2);
            acc += __shfl_xor(acc, 4);
            if (sub == 0) W3b[oid] = f2bf(acc);
        }
        if (i < NCLS * 8) {      // btv[c] = sum_k (sum_h b3[h,k]) * wp[k,c]
            int c = i >> 3, sub = i & 7;
            float acc = 0.f;
            for (int k = sub; k < O3; k += 8) {
                float bs = 0.f;
                #pragma unroll
                for (int hh = 0; hh < H3; hh++) bs += b3[hh * O3 + k];
                acc += bs * wp[k * NCLS + c];
            }
            acc += __shfl_xor(acc, 1);
            acc += __shfl_xor(acc, 2);
            acc += __shfl_xor(acc, 4);
            if (sub == 0) btv[c] = acc;
        }
    }
}

// ---- GEMM phase: C[MxN] = A[MxK] * BT[NxK]^T, grid-stride over 128x128 tiles ----
template <int MODE, bool SPLIT>
__device__ __forceinline__ void gemm_phase(
    unsigned short* __restrict__ sAh, unsigned short* __restrict__ sAl,
    unsigned short* __restrict__ sBh, unsigned short* __restrict__ sBl,
    const unsigned short* __restrict__ Ahi, const unsigned short* __restrict__ Alo,
    const unsigned short* __restrict__ Bhi, const unsigned short* __restrict__ Blo,
    unsigned short* __restrict__ Cbf, unsigned short* __restrict__ Qb,
    float* __restrict__ es, float* __restrict__ ed,
    const float* __restrict__ as_, const float* __restrict__ ad_,
    int M, int K, int N, int nbx) {
    int tid = threadIdx.x;
    int lane = tid & 63, wave = tid >> 6;
    int wr = (wave >> 1) * 64, wc = (wave & 1) * 64;
    int quad = lane >> 4, mr = lane & 15;
    int nby = (M + 127) >> 7;
    int ntiles = nbx * nby;

    for (int tile = blockIdx.x; tile < ntiles; tile += gridDim.x) {
        int row0 = (tile / nbx) * 128, col0 = (tile % nbx) * 128;

        floatx4 zero = {0.f, 0.f, 0.f, 0.f};
        floatx4 acc[4][4];
        #pragma unroll
        for (int i = 0; i < 4; i++)
            #pragma unroll
            for (int j = 0; j < 4; j++) acc[i][j] = zero;

        for (int k0 = 0; k0 < K; k0 += 32) {
            #pragma unroll
            for (int ch = 0; ch < 2; ch++) {
                int linear = (ch * 256 + tid) * 8;   // 128*32 = 4096 elements
                int r = linear >> 5, c = linear & 31;
                uint4 vh, vl;
                int gr = row0 + r;
                if (gr < M) {
                    vh = *(const uint4*)(Ahi + (size_t)gr * K + k0 + c);
                    if (SPLIT) vl = *(const uint4*)(Alo + (size_t)gr * K + k0 + c);
                } else { vh = uint4{0, 0, 0, 0}; vl = uint4{0, 0, 0, 0}; }
                *(uint4*)&sAh[r * LDA + c] = vh;
                if (SPLIT) *(uint4*)&sAl[r * LDA + c] = vl;
                int gn = col0 + r;
                if (gn < N) {
                    vh = *(const uint4*)(Bhi + (size_t)gn * K + k0 + c);
                    if (SPLIT) vl = *(const uint4*)(Blo + (size_t)gn * K + k0 + c);
                } else { vh = uint4{0, 0, 0, 0}; vl = uint4{0, 0, 0, 0}; }
                *(uint4*)&sBh[r * LDA + c] = vh;
                if (SPLIT) *(uint4*)&sBl[r * LDA + c] = vl;
            }
            __syncthreads();

            short8 ah[4], al[4], bh[4], bl[4];
            #pragma unroll
            for (int i = 0; i < 4; i++) {
                int ar = wr + i * 16 + mr;
                ah[i] = *(const short8*)&sAh[ar * LDA + quad * 8];
                if (SPLIT) al[i] = *(const short8*)&sAl[ar * LDA + quad * 8];
                int br = wc + i * 16 + mr;
                bh[i] = *(const short8*)&sBh[br * LDA + quad * 8];
                if (SPLIT) bl[i] = *(const short8*)&sBl[br * LDA + quad * 8];
            }
            #pragma unroll
            for (int i = 0; i < 4; i++)
                #pragma unroll
                for (int j = 0; j < 4; j++) {
                    acc[i][j] = __builtin_amdgcn_mfma_f32_16x16x32_bf16(ah[i], bh[j], acc[i][j], 0, 0, 0);
                    if (SPLIT) {
                        acc[i][j] = __builtin_amdgcn_mfma_f32_16x16x32_bf16(ah[i], bl[j], acc[i][j], 0, 0, 0);
                        acc[i][j] = __builtin_amdgcn_mfma_f32_16x16x32_bf16(al[i], bh[j], acc[i][j], 0, 0, 0);
                    }
                }
            __syncthreads();
        }

        #pragma unroll
        for (int i = 0; i < 4; i++) {
            #pragma unroll
            for (int j = 0; j < 4; j++) {
                int gc = col0 + wc + j * 16 + mr;
                if (gc >= N) continue;
                int gr0 = row0 + wr + i * 16 + quad * 4;
                #pragma unroll
                for (int r = 0; r < 4; r++) {
                    int gr = gr0 + r;
                    if (gr >= M) continue;
                    float v = acc[i][j][r];
                    if (MODE == 0) {
                        Cbf[(size_t)gr * D1 + gc] = f2bf(v);
                    } else {
                        if (gc < NQ)            Qb[(size_t)gr * NQ + gc] = f2bf(v);
                        else if (gc < NQ + H3)  es[(size_t)gr * H3 + (gc - NQ)] = v;
                        else                    ed[(size_t)gr * H3 + (gc - NQ - H3)] = v;
                    }
                }
            }
        }

        if (MODE == 0) {
            // fused logits: this wave owns head hx for rows wr..wr+63
            int hx = 2 * (tile % nbx) + (wave & 1);
            float asr[4], adr[4];
            #pragma unroll
            for (int j = 0; j < 4; j++) {
                asr[j] = as_[hx * 64 + j * 16 + mr];
                adr[j] = ad_[hx * 64 + j * 16 + mr];
            }
            #pragma unroll
            for (int i = 0; i < 4; i++) {
                #pragma unroll
                for (int r = 0; r < 4; r++) {
                    float ps = 0.f, pd = 0.f;
                    #pragma unroll
                    for (int j = 0; j < 4; j++) {
                        float v = acc[i][j][r];
                        ps += v * asr[j];
                        pd += v * adr[j];
                    }
                    #pragma unroll
                    for (int m2 = 8; m2 >= 1; m2 >>= 1) {
                        ps += __shfl_xor(ps, m2);
                        pd += __shfl_xor(pd, m2);
                    }
                    int gr = row0 + wr + i * 16 + quad * 4 + r;
                    if (mr == 0 && gr < M) {
                        es[gr * 4 + hx] = ps;
                        ed[gr * 4 + hx] = pd;
                    }
                }
            }
        }
    }
}

// ---- conv1/2 aggregation: half-wave per edge, 8 features per lane ----
__device__ __forceinline__ void agg12_phase(
    const unsigned short* __restrict__ P, const float* __restrict__ es,
    const float* __restrict__ ed, const int* __restrict__ cnt,
    const int* __restrict__ csr, const float* __restrict__ bias,
    unsigned short* __restrict__ outHi) {
    int wave = threadIdx.x >> 6, lane = threadIdx.x & 63;
    int hi = lane >> 5;            // which edge of the pair
    int fl = lane & 31;            // feature-lane: features fl*8 .. fl*8+7
    int hq = fl >> 3;              // head of those features
    int f0 = fl * 8;
    float bv[8];
    #pragma unroll
    for (int j = 0; j < 8; j++) bv[j] = bias[f0 + j];
    for (int dst = blockIdx.x * 4 + wave; dst < NN; dst += gridDim.x * 4) {
        int s0 = dst * CAP, s1 = s0 + cnt[dst];
        float edv = ed[dst * 4 + hq];
        float sum = 0.f;
        float acc[8];
        #pragma unroll
        for (int j = 0; j < 8; j++) acc[j] = 0.f;
        int s = s0;
        for (; s + 8 <= s1; s += 8) {      // 4 pairs = 8 edges
            int si[4]; float ev[4]; ushort8 pp[4];
            #pragma unroll
            for (int u = 0; u < 4; u++) si[u] = csr[s + 2 * u + hi];
            #pragma unroll
            for (int u = 0; u < 4; u++) {
                ev[u] = es[si[u] * 4 + hq] + edv;
                pp[u] = *(const ushort8*)(P + (size_t)si[u] * D1 + f0);
            }
            #pragma unroll
            for (int u = 0; u < 4; u++) {
                float e = __expf(lrelu(ev[u]));
                sum += e;
                #pragma unroll
                for (int j = 0; j < 8; j++) acc[j] += e * bf2f(pp[u][j]);
            }
        }
        for (; s + 4 <= s1; s += 4) {      // 2 pairs = 4 edges
            int si[2]; float ev[2]; ushort8 pp[2];
            #pragma unroll
            for (int u = 0; u < 2; u++) si[u] = csr[s + 2 * u + hi];
            #pragma unroll
            for (int u = 0; u < 2; u++) {
                ev[u] = es[si[u] * 4 + hq] + edv;
                pp[u] = *(const ushort8*)(P + (size_t)si[u] * D1 + f0);
            }
            #pragma unroll
            for (int u = 0; u < 2; u++) {
                float e = __expf(lrelu(ev[u]));
                sum += e;
                #pragma unroll
                for (int j = 0; j < 8; j++) acc[j] += e * bf2f(pp[u][j]);
            }
        }
        for (; s < s1; s += 2) {           // masked final pair (1-2 edges)
            int idx = s + hi;
            bool v = idx < s1;
            int si = csr[v ? idx : s];
            float evv = es[si * 4 + hq] + edv;
            ushort8 p8 = *(const ushort8*)(P + (size_t)si * D1 + f0);
            float e = v ? __expf(lrelu(evv)) : 0.f;
            sum += e;
            #pragma unroll
            for (int j = 0; j < 8; j++) acc[j] += e * bf2f(p8[j]);
        }
        sum += __shfl_xor(sum, 32);
        #pragma unroll
        for (int j = 0; j < 8; j++) acc[j] += __shfl_xor(acc[j], 32);
        float inv = 1.f / sum;
        if (lane < 32) {
            ushort8 o8;
            #pragma unroll
            for (int j = 0; j < 8; j++) {
                float a = acc[j] * inv + bv[j];
                a = a > 0.f ? a : expm1f(a);
                o8[j] = f2bf(a);
            }
            *(ushort8*)(outHi + (size_t)dst * D1 + f0) = o8;
        }
    }
}

// ---- conv3 aggregation: one-pass softmax + bf16 Q-gather + pool/classify ----
__device__ __forceinline__ void agg3q_phase(
    const unsigned short* __restrict__ Qb, const float* __restrict__ es,
    const float* __restrict__ ed, const int* __restrict__ cnt,
    const int* __restrict__ csr, const int* __restrict__ batch,
    float* __restrict__ G) {
    int wave = threadIdx.x >> 6, lane = threadIdx.x & 63;
    bool act = lane < NQ;
    int h = act ? (lane / NCLS) : 0;
    int q = act ? lane : 0;
    for (int dst = blockIdx.x * 4 + wave; dst < NN; dst += gridDim.x * 4) {
        int b = batch[dst];
        int s0 = dst * CAP, s1 = s0 + cnt[dst];
        float edv = act ? ed[dst * H3 + h] : 0.f;
        float sum = 0.f, acc = 0.f;
        int s = s0;
        for (; s + 8 <= s1; s += 8) {
            int si[8];
            #pragma unroll
            for (int u = 0; u < 8; u++) si[u] = csr[s + u];
            float vv[8], qq[8];
            #pragma unroll
            for (int u = 0; u < 8; u++) {
                vv[u] = es[si[u] * H3 + h] + edv;
                qq[u] = bf2f(Qb[(size_t)si[u] * NQ + q]);
            }
            #pragma unroll
            for (int u = 0; u < 8; u++) {
                float e = __expf(lrelu(vv[u]));
                sum += e;
                acc += e * qq[u];
            }
        }
        for (; s + 2 <= s1; s += 2) {
            int sa = csr[s], sb = csr[s + 1];
            float va = es[sa * H3 + h] + edv;
            float vb = es[sb * H3 + h] + edv;
            float qa = bf2f(Qb[(size_t)sa * NQ + q]);
            float qb = bf2f(Qb[(size_t)sb * NQ + q]);
            float ea = __expf(lrelu(va));
            float eb = __expf(lrelu(vb));
            sum += ea + eb;
            acc += ea * qa + eb * qb;
        }
        for (; s < s1; s++) {
            int sa = csr[s];
            float va = es[sa * H3 + h] + edv;
            float qa = bf2f(Qb[(size_t)sa * NQ + q]);
            float ea = __expf(lrelu(va));
            sum += ea;
            acc += ea * qa;
        }
        acc *= 1.f / sum;
        float av = act ? acc : 0.f;
        float tot = av;
        #pragma unroll
        for (int h2 = 1; h2 < H3; h2++) tot += __shfl(av, lane + h2 * NCLS);
        if (lane < NCLS) atomicAdd(&G[b * NCLS + lane], tot);
    }
}

// ==================== persistent mega-kernel (custom barriers) ====================

struct MegaArgs {
    const int *x, *dep, *ei, *batch;
    const float *nemb, *demb, *w1, *as1, *ad1, *b1, *w2, *as2, *ad2, *b2;
    const float *w3, *as3, *ad3, *b3, *wp, *bp;
    float* out;
    unsigned short *Hb, *H0lo, *W1hi, *W1lo, *W2b, *W3b, *Pb, *Qb;
    float *G, *es, *ed, *btv;
    int *cnt, *csr, *gs, *ge, *bar;
};

__global__ __launch_bounds__(256, 2) void mega_kernel(MegaArgs a) {
    __shared__ unsigned short sAh[128 * LDA], sBh[128 * LDA];
    __shared__ unsigned short sAl[128 * LDA], sBl[128 * LDA];
    __shared__ int s_last;

    phase_setup(a.x, a.dep, a.ei, a.batch, a.nemb, a.demb, a.w1, a.w2, a.w3,
                a.as3, a.ad3, a.wp, a.b3, a.Hb, a.H0lo, a.W1hi, a.W1lo, a.W2b, a.W3b,
                a.btv, a.cnt, a.csr, a.gs, a.ge);
    gbar(a.bar, 0);

    gemm_phase<0, true>(sAh, sAl, sBh, sBl, a.Hb, a.H0lo, a.W1hi, a.W1lo,
                        a.Pb, nullptr, a.es, a.ed, a.as1, a.ad1, NN, EMB, D1, 2);
    gbar(a.bar, 1);

    agg12_phase(a.Pb, a.es, a.ed, a.cnt, a.csr, a.b1, a.Hb);
    gbar(a.bar, 2);

    gemm_phase<0, false>(sAh, sAl, sBh, sBl, a.Hb, nullptr, a.W2b, nullptr,
                         a.Pb, nullptr, a.es, a.ed, a.as2, a.ad2, NN, D1, D1, 2);
    gbar(a.bar, 3);

    agg12_phase(a.Pb, a.es, a.ed, a.cnt, a.csr, a.b2, a.Hb);
    gbar(a.bar, 4);

    gemm_phase<1, false>(sAh, sAl, sBh, sBl, a.Hb, nullptr, a.W3b, nullptr,
                         nullptr, a.Qb, a.es, a.ed, nullptr, nullptr, NN, D1, N3, 1);
    gbar(a.bar, 5);

    agg3q_phase(a.Qb, a.es, a.ed, a.cnt, a.csr, a.batch, a.G);

    // last-block pattern for the tiny final phase (saves a full barrier)
    __syncthreads();
    if (threadIdx.x == 0) {
        __threadfence();
        int old = atomicAdd(&a.bar[6 * 32], 1);
        int last = (old == (int)gridDim.x - 1) ? 1 : 0;
        if (last) __threadfence();   // acquire: invalidate L2 so G reads are fresh
        s_last = last;
    }
    __syncthreads();
    if (s_last) {
        for (int i = threadIdx.x; i < NB * NCLS; i += blockDim.x) {
            int b = i / NCLS, c = i % NCLS;
            int cntn = a.ge[b] - a.gs[b];
            float o = a.bp[c];
            if (cntn > 0)
                o += a.G[i] / (6.f * (float)cntn) + a.btv[c] * (1.f / 6.f);
            a.out[i] = o;
        }
    }
}

// ==================== launch ====================

extern "C" void kernel_launch(void* const* d_in, const int* in_sizes, int n_in,
                              void* d_out, int out_size, void* d_ws, size_t ws_size,
                              hipStream_t stream) {
    MegaArgs a;
    a.x     = (const int*)d_in[0];
    a.dep   = (const int*)d_in[1];
    a.ei    = (const int*)d_in[2];
    a.batch = (const int*)d_in[3];
    a.nemb  = (const float*)d_in[4];
    a.demb  = (const float*)d_in[5];
    a.w1    = (const float*)d_in[6];
    a.as1   = (const float*)d_in[7];
    a.ad1   = (const float*)d_in[8];
    a.b1    = (const float*)d_in[9];
    a.w2    = (const float*)d_in[10];
    a.as2   = (const float*)d_in[11];
    a.ad2   = (const float*)d_in[12];
    a.b2    = (const float*)d_in[13];
    a.w3    = (const float*)d_in[14];
    a.as3   = (const float*)d_in[15];
    a.ad3   = (const float*)d_in[16];
    a.b3    = (const float*)d_in[17];
    a.wp    = (const float*)d_in[18];
    a.bp    = (const float*)d_in[19];
    a.out   = (float*)d_out;

    char* ws = (char*)d_ws;
    size_t off = 0;
    auto alloc = [&](size_t bytes) -> void* {
        void* p = ws + off;
        off += (bytes + 255) & ~(size_t)255;
        return p;
    };
    a.Hb   = (unsigned short*)alloc((size_t)NN * D1 * 2);     // H0 (stride 64) then H1/H2 (stride 256)
    a.H0lo = (unsigned short*)alloc((size_t)NN * EMB * 2);
    a.W1hi = (unsigned short*)alloc((size_t)D1 * EMB * 2);
    a.W1lo = (unsigned short*)alloc((size_t)D1 * EMB * 2);
    a.W2b  = (unsigned short*)alloc((size_t)D1 * D1 * 2);
    a.W3b  = (unsigned short*)alloc((size_t)N3 * D1 * 2);
    a.Pb   = (unsigned short*)alloc((size_t)NN * D1 * 2);
    a.Qb   = (unsigned short*)alloc(((size_t)NN * NQ + 64) * 2);
    a.es   = (float*)alloc((size_t)NN * 6 * 4);
    a.ed   = (float*)alloc((size_t)NN * 6 * 4);
    a.csr  = (int*)alloc((size_t)NN * CAP * 4);
    a.btv  = (float*)alloc((size_t)NCLS * 4);
    // ---- contiguous zero-region (one hipMemsetAsync covers all of it) ----
    char* zstart = ws + off;
    a.G    = (float*)alloc((size_t)NB * NCLS * 4);
    a.gs   = (int*)alloc((size_t)NB * 4);
    a.ge   = (int*)alloc((size_t)NB * 4);
    a.cnt  = (int*)alloc((size_t)NN * 4);
    a.bar  = (int*)alloc((size_t)8 * 32 * 4);
    size_t zbytes = (size_t)((ws + off) - zstart);

    // grid sizing: normal launch, co-residency guaranteed via occupancy query
    static int s_grid = 0;
    if (s_grid == 0) {
        int dev = 0;
        (void)hipGetDevice(&dev);
        int cus = 0;
        if (hipDeviceGetAttribute(&cus, hipDeviceAttributeMultiprocessorCount, dev) != hipSuccess || cus <= 0)
            cus = 256;
        int occ = 0;
        if (hipOccupancyMaxActiveBlocksPerMultiprocessor(&occ, (const void*)mega_kernel, 256, 0) != hipSuccess || occ <= 0)
            occ = 1;
        if (occ > 4) occ = 4;
        long long g = (long long)cus * occ;
        if (g > 1024) g = 1024;
        s_grid = (int)g;
    }

    hipMemsetAsync(zstart, 0, zbytes, stream);
    hipLaunchKernelGGL(mega_kernel, dim3(s_grid), dim3(256), 0, stream, a);
}

// Round 4
// 294.415 us; speedup vs baseline: 2.3486x; 1.8867x over previous
//
#include <hip/hip_runtime.h>
#include <hip/hip_bf16.h>
#include <math.h>

#define NN   30000
#define NE   300000
#define ETOT 330000   // NE + NN self loops
#define NB   300
#define EMB  64
#define D1   256      // 4 heads * 64
#define H1   4
#define H3   6
#define O3   121
#define D3   726      // 6 * 121
#define NQ   60       // 6 heads x 10 classes (pre-projected conv3 output)
#define N3   72       // NQ + 6 (es) + 6 (ed)
#define NCLS 10
#define CAP  64       // padded CSR slots per dst (max degree ~25 for this dataset)
#define LDA  40

typedef __attribute__((ext_vector_type(8))) short short8;
typedef __attribute__((ext_vector_type(8))) unsigned short ushort8;
typedef __attribute__((ext_vector_type(4))) float floatx4;

static inline int ceil_div(int a, int b) { return (a + b - 1) / b; }

__device__ inline void split_bf16(float f, unsigned short& hi, unsigned short& lo) {
    __hip_bfloat16 h = __float2bfloat16(f);
    float fh = __bfloat162float(h);
    __hip_bfloat16 l = __float2bfloat16(f - fh);
    hi = __builtin_bit_cast(unsigned short, h);
    lo = __builtin_bit_cast(unsigned short, l);
}

__device__ inline float bf2f(unsigned short u) {
    return __builtin_bit_cast(float, (unsigned int)u << 16);
}

__device__ inline unsigned short f2bf(float f) {
    return __builtin_bit_cast(unsigned short, __float2bfloat16(f));
}

__device__ inline float lrelu(float v) { return v > 0.f ? v : 0.2f * v; }

// ---------------- fused setup: node encode + CSR fill + ranges + weight prep + btv ----
// (cnt/G/gs/ge/bar zeroed by a pre-launch hipMemsetAsync on a contiguous region)

__global__ void setup_kernel(const int* __restrict__ x, const int* __restrict__ dep,
                             const int* __restrict__ ei, const int* __restrict__ batch,
                             const float* __restrict__ nemb, const float* __restrict__ demb,
                             const float* __restrict__ w1, const float* __restrict__ w2,
                             const float* __restrict__ w3, const float* __restrict__ as3,
                             const float* __restrict__ ad3, const float* __restrict__ wp,
                             const float* __restrict__ b3,
                             unsigned short* __restrict__ H0hi, unsigned short* __restrict__ H0lo,
                             unsigned short* __restrict__ W1hi, unsigned short* __restrict__ W1lo,
                             unsigned short* __restrict__ W2b, unsigned short* __restrict__ W3b,
                             float* __restrict__ btv,
                             int* __restrict__ cnt, int* __restrict__ csr,
                             int* __restrict__ gs, int* __restrict__ ge) {
    int i = blockIdx.x * blockDim.x + threadIdx.x;
    if (i < NN * EMB) {
        int n = i >> 6, d = i & 63;
        float v = nemb[x[n] * EMB + d] + demb[dep[n] * EMB + d];
        split_bf16(v, H0hi[i], H0lo[i]);
    }
    if (i < ETOT) {
        int src, dst;
        if (i < NE) { src = ei[i]; dst = ei[NE + i]; }
        else        { src = i - NE; dst = src; }
        int slot = atomicAdd(&cnt[dst], 1);
        csr[dst * CAP + slot] = src;
    }
    if (i < NN) {
        int b = batch[i];
        if (i == 0 || batch[i - 1] != b) gs[b] = i;
        if (i == NN - 1 || batch[i + 1] != b) ge[b] = i + 1;
    }
    if (i < EMB * D1) {
        int k = i / D1, n = i % D1;
        unsigned short h, l;
        split_bf16(w1[i], h, l);
        W1hi[n * EMB + k] = h;
        W1lo[n * EMB + k] = l;
    }
    if (i < D1 * D1) {
        int k = i / D1, n = i % D1;
        W2b[n * D1 + k] = f2bf(w2[i]);
    }
    if (i < N3 * D1 * 8) {   // W3 fold: 8-lane groups, 147456 threads
        int oid = i >> 3, sub = i & 7;
        int n = oid / D1, k = oid % D1;
        const float* wrow = w3 + (size_t)k * D3;
        float acc = 0.f;
        if (n < NQ) {
            int h = n / NCLS, c = n % NCLS;
            const float* wr = wrow + h * O3;
            for (int j = sub; j < O3; j += 8) acc += wr[j] * wp[j * NCLS + c];
        } else if (n < NQ + H3) {
            int h = n - NQ;
            const float* wr = wrow + h * O3;
            for (int j = sub; j < O3; j += 8) acc += wr[j] * as3[h * O3 + j];
        } else {
            int h = n - NQ - H3;
            const float* wr = wrow + h * O3;
            for (int j = sub; j < O3; j += 8) acc += wr[j] * ad3[h * O3 + j];
        }
        acc += __shfl_xor(acc, 1);
        acc += __shfl_xor(acc, 2);
        acc += __shfl_xor(acc, 4);
        if (sub == 0) W3b[oid] = f2bf(acc);
    }
    if (i < NCLS * 8) {      // btv[c] = sum_k (sum_h b3[h,k]) * wp[k,c]
        int c = i >> 3, sub = i & 7;
        float acc = 0.f;
        for (int k = sub; k < O3; k += 8) {
            float bs = 0.f;
            #pragma unroll
            for (int hh = 0; hh < H3; hh++) bs += b3[hh * O3 + k];
            acc += bs * wp[k * NCLS + c];
        }
        acc += __shfl_xor(acc, 1);
        acc += __shfl_xor(acc, 2);
        acc += __shfl_xor(acc, 4);
        if (sub == 0) btv[c] = acc;
    }
}

// ---------------- MFMA GEMM: C[MxN] = A[MxK] * BT[NxK]^T ----------------
// SPLIT=true : split-bf16 A and B (3 MFMA per frag) — conv1 only.
// MODE 0: bf16 P out (N=256) + fused es/ed logits epilogue (as_/ad_ [4][64]).
// MODE 1: bf16 Q[.,60] + fp32 es[.,6] + ed[.,6] (conv3 pre-folded B).

template <int MODE, bool SPLIT>
__global__ __launch_bounds__(256) void gemm_mfma_kernel(
    const unsigned short* __restrict__ Ahi, const unsigned short* __restrict__ Alo,
    const unsigned short* __restrict__ Bhi, const unsigned short* __restrict__ Blo,
    unsigned short* __restrict__ Cbf, unsigned short* __restrict__ Qb,
    float* __restrict__ es, float* __restrict__ ed,
    const float* __restrict__ as_, const float* __restrict__ ad_,
    int M, int K, int N) {
    __shared__ unsigned short sAh[128 * LDA], sBh[128 * LDA];
    __shared__ unsigned short sAl[SPLIT ? 128 * LDA : 1], sBl[SPLIT ? 128 * LDA : 1];
    int tid = threadIdx.x;
    int lane = tid & 63, wave = tid >> 6;
    int wr = (wave >> 1) * 64, wc = (wave & 1) * 64;
    int quad = lane >> 4, mr = lane & 15;
    int row0 = blockIdx.y * 128, col0 = blockIdx.x * 128;

    floatx4 zero = {0.f, 0.f, 0.f, 0.f};
    floatx4 acc[4][4];
    #pragma unroll
    for (int i = 0; i < 4; i++)
        #pragma unroll
        for (int j = 0; j < 4; j++) acc[i][j] = zero;

    for (int k0 = 0; k0 < K; k0 += 32) {
        #pragma unroll
        for (int ch = 0; ch < 2; ch++) {
            int linear = (ch * 256 + tid) * 8;   // 128*32 = 4096 elements
            int r = linear >> 5, c = linear & 31;
            uint4 vh, vl;
            int gr = row0 + r;
            if (gr < M) {
                vh = *(const uint4*)(Ahi + (size_t)gr * K + k0 + c);
                if (SPLIT) vl = *(const uint4*)(Alo + (size_t)gr * K + k0 + c);
            } else { vh = uint4{0, 0, 0, 0}; vl = uint4{0, 0, 0, 0}; }
            *(uint4*)&sAh[r * LDA + c] = vh;
            if (SPLIT) *(uint4*)&sAl[r * LDA + c] = vl;
            int gn = col0 + r;
            if (gn < N) {
                vh = *(const uint4*)(Bhi + (size_t)gn * K + k0 + c);
                if (SPLIT) vl = *(const uint4*)(Blo + (size_t)gn * K + k0 + c);
            } else { vh = uint4{0, 0, 0, 0}; vl = uint4{0, 0, 0, 0}; }
            *(uint4*)&sBh[r * LDA + c] = vh;
            if (SPLIT) *(uint4*)&sBl[r * LDA + c] = vl;
        }
        __syncthreads();

        short8 ah[4], al[4], bh[4], bl[4];
        #pragma unroll
        for (int i = 0; i < 4; i++) {
            int ar = wr + i * 16 + mr;
            ah[i] = *(const short8*)&sAh[ar * LDA + quad * 8];
            if (SPLIT) al[i] = *(const short8*)&sAl[ar * LDA + quad * 8];
            int br = wc + i * 16 + mr;
            bh[i] = *(const short8*)&sBh[br * LDA + quad * 8];
            if (SPLIT) bl[i] = *(const short8*)&sBl[br * LDA + quad * 8];
        }
        #pragma unroll
        for (int i = 0; i < 4; i++)
            #pragma unroll
            for (int j = 0; j < 4; j++) {
                acc[i][j] = __builtin_amdgcn_mfma_f32_16x16x32_bf16(ah[i], bh[j], acc[i][j], 0, 0, 0);
                if (SPLIT) {
                    acc[i][j] = __builtin_amdgcn_mfma_f32_16x16x32_bf16(ah[i], bl[j], acc[i][j], 0, 0, 0);
                    acc[i][j] = __builtin_amdgcn_mfma_f32_16x16x32_bf16(al[i], bh[j], acc[i][j], 0, 0, 0);
                }
            }
        __syncthreads();
    }

    #pragma unroll
    for (int i = 0; i < 4; i++) {
        #pragma unroll
        for (int j = 0; j < 4; j++) {
            int gc = col0 + wc + j * 16 + mr;
            if (gc >= N) continue;
            int gr0 = row0 + wr + i * 16 + quad * 4;
            #pragma unroll
            for (int r = 0; r < 4; r++) {
                int gr = gr0 + r;
                if (gr >= M) continue;
                float v = acc[i][j][r];
                if (MODE == 0) {
                    Cbf[(size_t)gr * D1 + gc] = f2bf(v);
                } else {
                    if (gc < NQ)            Qb[(size_t)gr * NQ + gc] = f2bf(v);
                    else if (gc < NQ + H3)  es[(size_t)gr * H3 + (gc - NQ)] = v;
                    else                    ed[(size_t)gr * H3 + (gc - NQ - H3)] = v;
                }
            }
        }
    }

    if (MODE == 0) {
        // fused logits: this wave owns head hx for rows wr..wr+63
        int hx = 2 * blockIdx.x + (wave & 1);
        float asr[4], adr[4];
        #pragma unroll
        for (int j = 0; j < 4; j++) {
            asr[j] = as_[hx * 64 + j * 16 + mr];
            adr[j] = ad_[hx * 64 + j * 16 + mr];
        }
        #pragma unroll
        for (int i = 0; i < 4; i++) {
            #pragma unroll
            for (int r = 0; r < 4; r++) {
                float ps = 0.f, pd = 0.f;
                #pragma unroll
                for (int j = 0; j < 4; j++) {
                    float v = acc[i][j][r];
                    ps += v * asr[j];
                    pd += v * adr[j];
                }
                #pragma unroll
                for (int m2 = 8; m2 >= 1; m2 >>= 1) {
                    ps += __shfl_xor(ps, m2);
                    pd += __shfl_xor(pd, m2);
                }
                int gr = row0 + wr + i * 16 + quad * 4 + r;
                if (mr == 0 && gr < M) {
                    es[gr * 4 + hx] = ps;
                    ed[gr * 4 + hx] = pd;
                }
            }
        }
    }
}

// ---------------- conv1/2: one-pass softmax aggregation ----------------
// Half-wave per edge: lanes 0-31 even edge, 32-63 odd edge; 8 features/lane
// (ushort8 = 16B loads). shfl_xor(32) merges the two half-softmax partials.

__global__ __launch_bounds__(256) void aggregate12_kernel(
    const unsigned short* __restrict__ P, const float* __restrict__ es,
    const float* __restrict__ ed, const int* __restrict__ cnt,
    const int* __restrict__ csr, const float* __restrict__ bias,
    unsigned short* __restrict__ outHi) {
    int wave = threadIdx.x >> 6, lane = threadIdx.x & 63;
    int wid = blockIdx.x * 4 + wave;
    int hi = lane >> 5;            // which edge of the pair
    int fl = lane & 31;            // feature-lane: features fl*8 .. fl*8+7
    int hq = fl >> 3;              // head of those features
    int f0 = fl * 8;
    float bv[8];
    #pragma unroll
    for (int j = 0; j < 8; j++) bv[j] = bias[f0 + j];
    #pragma unroll 1
    for (int t = 0; t < 4; t++) {
        int dst = wid * 4 + t;
        int s0 = dst * CAP, s1 = s0 + cnt[dst];
        float edv = ed[dst * 4 + hq];
        float sum = 0.f;
        float acc[8];
        #pragma unroll
        for (int j = 0; j < 8; j++) acc[j] = 0.f;
        int s = s0;
        for (; s + 8 <= s1; s += 8) {      // 4 pairs = 8 edges
            int si[4]; float ev[4]; ushort8 pp[4];
            #pragma unroll
            for (int u = 0; u < 4; u++) si[u] = csr[s + 2 * u + hi];
            #pragma unroll
            for (int u = 0; u < 4; u++) {
                ev[u] = es[si[u] * 4 + hq] + edv;
                pp[u] = *(const ushort8*)(P + (size_t)si[u] * D1 + f0);
            }
            #pragma unroll
            for (int u = 0; u < 4; u++) {
                float e = __expf(lrelu(ev[u]));
                sum += e;
                #pragma unroll
                for (int j = 0; j < 8; j++) acc[j] += e * bf2f(pp[u][j]);
            }
        }
        for (; s + 4 <= s1; s += 4) {      // 2 pairs = 4 edges
            int si[2]; float ev[2]; ushort8 pp[2];
            #pragma unroll
            for (int u = 0; u < 2; u++) si[u] = csr[s + 2 * u + hi];
            #pragma unroll
            for (int u = 0; u < 2; u++) {
                ev[u] = es[si[u] * 4 + hq] + edv;
                pp[u] = *(const ushort8*)(P + (size_t)si[u] * D1 + f0);
            }
            #pragma unroll
            for (int u = 0; u < 2; u++) {
                float e = __expf(lrelu(ev[u]));
                sum += e;
                #pragma unroll
                for (int j = 0; j < 8; j++) acc[j] += e * bf2f(pp[u][j]);
            }
        }
        for (; s < s1; s += 2) {           // masked final pair (1-2 edges)
            int idx = s + hi;
            bool v = idx < s1;
            int si = csr[v ? idx : s];
            float evv = es[si * 4 + hq] + edv;
            ushort8 p8 = *(const ushort8*)(P + (size_t)si * D1 + f0);
            float e = v ? __expf(lrelu(evv)) : 0.f;
            sum += e;
            #pragma unroll
            for (int j = 0; j < 8; j++) acc[j] += e * bf2f(p8[j]);
        }
        sum += __shfl_xor(sum, 32);
        #pragma unroll
        for (int j = 0; j < 8; j++) acc[j] += __shfl_xor(acc[j], 32);
        float inv = 1.f / sum;
        if (lane < 32) {
            ushort8 o8;
            #pragma unroll
            for (int j = 0; j < 8; j++) {
                float a = acc[j] * inv + bv[j];
                a = a > 0.f ? a : expm1f(a);
                o8[j] = f2bf(a);
            }
            *(ushort8*)(outHi + (size_t)dst * D1 + f0) = o8;
        }
    }
}

// ---------------- conv3: one-pass softmax + Q-gather + pool + fused classifier ----

__global__ __launch_bounds__(256) void aggregate3q_kernel(
    const unsigned short* __restrict__ Qb, const float* __restrict__ es,
    const float* __restrict__ ed, const int* __restrict__ cnt,
    const int* __restrict__ csr, const int* __restrict__ batch,
    float* __restrict__ G,
    const int* __restrict__ gs, const int* __restrict__ ge,
    const float* __restrict__ btv, const float* __restrict__ bp,
    float* __restrict__ out, int* __restrict__ bar) {
    __shared__ int s_last;
    int wave = threadIdx.x >> 6, lane = threadIdx.x & 63;
    int wid = blockIdx.x * 4 + wave;
    bool act = lane < NQ;
    int h = act ? (lane / NCLS) : 0;
    int q = act ? lane : 0;
    #pragma unroll 1
    for (int t = 0; t < 4; t++) {
        int dst = wid * 4 + t;
        int b = batch[dst];
        int s0 = dst * CAP, s1 = s0 + cnt[dst];
        float edv = act ? ed[dst * H3 + h] : 0.f;
        float sum = 0.f, acc = 0.f;
        int s = s0;
        for (; s + 8 <= s1; s += 8) {
            int si[8];
            #pragma unroll
            for (int u = 0; u < 8; u++) si[u] = csr[s + u];
            float vv[8], qq[8];
            #pragma unroll
            for (int u = 0; u < 8; u++) {
                vv[u] = es[si[u] * H3 + h] + edv;
                qq[u] = bf2f(Qb[(size_t)si[u] * NQ + q]);
            }
            #pragma unroll
            for (int u = 0; u < 8; u++) {
                float e = __expf(lrelu(vv[u]));
                sum += e;
                acc += e * qq[u];
            }
        }
        for (; s + 2 <= s1; s += 2) {
            int sa = csr[s], sb = csr[s + 1];
            float va = es[sa * H3 + h] + edv;
            float vb = es[sb * H3 + h] + edv;
            float qa = bf2f(Qb[(size_t)sa * NQ + q]);
            float qb = bf2f(Qb[(size_t)sb * NQ + q]);
            float ea = __expf(lrelu(va));
            float eb = __expf(lrelu(vb));
            sum += ea + eb;
            acc += ea * qa + eb * qb;
        }
        for (; s < s1; s++) {
            int sa = csr[s];
            float va = es[sa * H3 + h] + edv;
            float qa = bf2f(Qb[(size_t)sa * NQ + q]);
            float ea = __expf(lrelu(va));
            sum += ea;
            acc += ea * qa;
        }
        acc *= 1.f / sum;
        float av = act ? acc : 0.f;
        float tot = av;
        #pragma unroll
        for (int h2 = 1; h2 < H3; h2++) tot += __shfl(av, lane + h2 * NCLS);
        if (lane < NCLS) atomicAdd(&G[b * NCLS + lane], tot);
    }

    // fused final classifier: last block to finish does the [NB,NCLS] epilogue
    __syncthreads();
    if (threadIdx.x == 0) {
        __threadfence();
        int old = atomicAdd(bar, 1);
        int last = (old == (int)gridDim.x - 1) ? 1 : 0;
        if (last) __threadfence();   // acquire: G atomics from all blocks visible
        s_last = last;
    }
    __syncthreads();
    if (s_last) {
        for (int i = threadIdx.x; i < NB * NCLS; i += blockDim.x) {
            int b = i / NCLS, c = i % NCLS;
            int cntn = ge[b] - gs[b];
            float o = bp[c];
            if (cntn > 0)
                o += G[i] / (6.f * (float)cntn) + btv[c] * (1.f / 6.f);
            out[i] = o;
        }
    }
}

// ---------------- launch ----------------

extern "C" void kernel_launch(void* const* d_in, const int* in_sizes, int n_in,
                              void* d_out, int out_size, void* d_ws, size_t ws_size,
                              hipStream_t stream) {
    const int* x     = (const int*)d_in[0];
    const int* dep   = (const int*)d_in[1];
    const int* ei    = (const int*)d_in[2];
    const int* batch = (const int*)d_in[3];
    const float* nemb = (const float*)d_in[4];
    const float* demb = (const float*)d_in[5];
    const float* w1  = (const float*)d_in[6];
    const float* as1 = (const float*)d_in[7];
    const float* ad1 = (const float*)d_in[8];
    const float* b1  = (const float*)d_in[9];
    const float* w2  = (const float*)d_in[10];
    const float* as2 = (const float*)d_in[11];
    const float* ad2 = (const float*)d_in[12];
    const float* b2  = (const float*)d_in[13];
    const float* w3  = (const float*)d_in[14];
    const float* as3 = (const float*)d_in[15];
    const float* ad3 = (const float*)d_in[16];
    const float* b3  = (const float*)d_in[17];
    const float* wp  = (const float*)d_in[18];
    const float* bp  = (const float*)d_in[19];
    float* out = (float*)d_out;

    char* ws = (char*)d_ws;
    size_t off = 0;
    auto alloc = [&](size_t bytes) -> void* {
        void* p = ws + off;
        off += (bytes + 255) & ~(size_t)255;
        return p;
    };
    unsigned short* Hb   = (unsigned short*)alloc((size_t)NN * D1 * 2);     // H0 (stride 64) then H1/H2 (stride 256)
    unsigned short* H0lo = (unsigned short*)alloc((size_t)NN * EMB * 2);    // H0 lo (conv1 split A)
    unsigned short* W1hi = (unsigned short*)alloc((size_t)D1 * EMB * 2);
    unsigned short* W1lo = (unsigned short*)alloc((size_t)D1 * EMB * 2);
    unsigned short* W2b  = (unsigned short*)alloc((size_t)D1 * D1 * 2);
    unsigned short* W3b  = (unsigned short*)alloc((size_t)N3 * D1 * 2);
    unsigned short* Pb   = (unsigned short*)alloc((size_t)NN * D1 * 2);     // bf16 P (conv1/2)
    unsigned short* Qb   = (unsigned short*)alloc(((size_t)NN * NQ + 64) * 2);
    float* es   = (float*)alloc((size_t)NN * 6 * 4);
    float* ed   = (float*)alloc((size_t)NN * 6 * 4);
    int* csr    = (int*)alloc((size_t)NN * CAP * 4);                        // padded CSR
    float* btv  = (float*)alloc((size_t)NCLS * 4);
    // ---- contiguous zero-region (one hipMemsetAsync covers all of it) ----
    char* zstart = ws + off;
    float* G    = (float*)alloc((size_t)NB * NCLS * 4);
    int* gs     = (int*)alloc((size_t)NB * 4);
    int* ge     = (int*)alloc((size_t)NB * 4);
    int* cnt    = (int*)alloc((size_t)NN * 4);
    int* bar    = (int*)alloc((size_t)64 * 4);
    size_t zbytes = (size_t)((ws + off) - zstart);

    hipMemsetAsync(zstart, 0, zbytes, stream);

    // --- fused preprocessing (1 kernel) ---
    setup_kernel<<<ceil_div(NN * EMB, 256), 256, 0, stream>>>(
        x, dep, ei, batch, nemb, demb, w1, w2, w3, as3, ad3, wp, b3,
        Hb, H0lo, W1hi, W1lo, W2b, W3b, btv, cnt, csr, gs, ge);

    // --- conv1: [NN,64] -> [NN,256] split-bf16 GEMM, logits fused ---
    gemm_mfma_kernel<0, true><<<dim3(2, ceil_div(NN, 128)), 256, 0, stream>>>(
        Hb, H0lo, W1hi, W1lo, Pb, nullptr, es, ed, as1, ad1, NN, EMB, D1);
    aggregate12_kernel<<<NN / 16, 256, 0, stream>>>(Pb, es, ed, cnt, csr, b1, Hb);

    // --- conv2: [NN,256] -> [NN,256] plain bf16 GEMM, logits fused ---
    gemm_mfma_kernel<0, false><<<dim3(2, ceil_div(NN, 128)), 256, 0, stream>>>(
        Hb, nullptr, W2b, nullptr, Pb, nullptr, es, ed, as2, ad2, NN, D1, D1);
    aggregate12_kernel<<<NN / 16, 256, 0, stream>>>(Pb, es, ed, cnt, csr, b2, Hb);

    // --- conv3 folded: [NN,256] -> Qb[NN,60](bf16) + es/ed[NN,6] ---
    gemm_mfma_kernel<1, false><<<dim3(1, ceil_div(NN, 128)), 256, 0, stream>>>(
        Hb, nullptr, W3b, nullptr, nullptr, Qb, es, ed, nullptr, nullptr, NN, D1, N3);

    // --- conv3 aggregation + pool + fused final classifier (last-block) ---
    aggregate3q_kernel<<<NN / 16, 256, 0, stream>>>(
        Qb, es, ed, cnt, csr, batch, G, gs, ge, btv, bp, out, bar);
}

// Round 5
// 278.073 us; speedup vs baseline: 2.4866x; 1.0588x over previous
//
#include <hip/hip_runtime.h>
#include <hip/hip_bf16.h>
#include <math.h>

#define NN   30000
#define NE   300000
#define ETOT 330000   // NE + NN self loops
#define NB   300
#define EMB  64
#define D1   256      // 4 heads * 64
#define H1   4
#define H3   6
#define O3   121
#define D3   726      // 6 * 121
#define NQ   60       // 6 heads x 10 classes (pre-projected conv3 output)
#define N3   72       // NQ + 6 (es) + 6 (ed)
#define NCLS 10
#define CAP  64       // padded CSR slots per dst (max degree ~25 for this dataset)
#define LDA  40

typedef __attribute__((ext_vector_type(8))) short short8;
typedef __attribute__((ext_vector_type(8))) unsigned short ushort8;
typedef __attribute__((ext_vector_type(4))) float floatx4;

static inline int ceil_div(int a, int b) { return (a + b - 1) / b; }

__device__ inline void split_bf16(float f, unsigned short& hi, unsigned short& lo) {
    __hip_bfloat16 h = __float2bfloat16(f);
    float fh = __bfloat162float(h);
    __hip_bfloat16 l = __float2bfloat16(f - fh);
    hi = __builtin_bit_cast(unsigned short, h);
    lo = __builtin_bit_cast(unsigned short, l);
}

__device__ inline float bf2f(unsigned short u) {
    return __builtin_bit_cast(float, (unsigned int)u << 16);
}

__device__ inline unsigned short f2bf(float f) {
    return __builtin_bit_cast(unsigned short, __float2bfloat16(f));
}

__device__ inline float lrelu(float v) { return v > 0.f ? v : 0.2f * v; }

// ---------------- fused setup: node encode + CSR fill + ranges + weight prep + btv ----
// (cnt/G/gs/ge/bar zeroed by a pre-launch hipMemsetAsync on a contiguous region)

__global__ void setup_kernel(const int* __restrict__ x, const int* __restrict__ dep,
                             const int* __restrict__ ei, const int* __restrict__ batch,
                             const float* __restrict__ nemb, const float* __restrict__ demb,
                             const float* __restrict__ w1, const float* __restrict__ w2,
                             const float* __restrict__ w3, const float* __restrict__ as3,
                             const float* __restrict__ ad3, const float* __restrict__ wp,
                             const float* __restrict__ b3,
                             unsigned short* __restrict__ H0hi, unsigned short* __restrict__ H0lo,
                             unsigned short* __restrict__ W1hi, unsigned short* __restrict__ W1lo,
                             unsigned short* __restrict__ W2b, unsigned short* __restrict__ W3b,
                             float* __restrict__ btv,
                             int* __restrict__ cnt, int* __restrict__ csr,
                             int* __restrict__ gs, int* __restrict__ ge) {
    int i = blockIdx.x * blockDim.x + threadIdx.x;
    if (i < NN * EMB) {
        int n = i >> 6, d = i & 63;
        float v = nemb[x[n] * EMB + d] + demb[dep[n] * EMB + d];
        split_bf16(v, H0hi[i], H0lo[i]);
    }
    if (i < ETOT) {
        int src, dst;
        if (i < NE) { src = ei[i]; dst = ei[NE + i]; }
        else        { src = i - NE; dst = src; }
        int slot = atomicAdd(&cnt[dst], 1);
        csr[dst * CAP + slot] = src;
    }
    if (i < NN) {
        int b = batch[i];
        if (i == 0 || batch[i - 1] != b) gs[b] = i;
        if (i == NN - 1 || batch[i + 1] != b) ge[b] = i + 1;
    }
    if (i < EMB * D1) {
        int k = i / D1, n = i % D1;
        unsigned short h, l;
        split_bf16(w1[i], h, l);
        W1hi[n * EMB + k] = h;
        W1lo[n * EMB + k] = l;
    }
    if (i < D1 * D1) {
        int k = i / D1, n = i % D1;
        W2b[n * D1 + k] = f2bf(w2[i]);
    }
    if (i < N3 * D1 * 8) {   // W3 fold: 8-lane groups, 147456 threads
        int oid = i >> 3, sub = i & 7;
        int n = oid / D1, k = oid % D1;
        const float* wrow = w3 + (size_t)k * D3;
        float acc = 0.f;
        if (n < NQ) {
            int h = n / NCLS, c = n % NCLS;
            const float* wr = wrow + h * O3;
            for (int j = sub; j < O3; j += 8) acc += wr[j] * wp[j * NCLS + c];
        } else if (n < NQ + H3) {
            int h = n - NQ;
            const float* wr = wrow + h * O3;
            for (int j = sub; j < O3; j += 8) acc += wr[j] * as3[h * O3 + j];
        } else {
            int h = n - NQ - H3;
            const float* wr = wrow + h * O3;
            for (int j = sub; j < O3; j += 8) acc += wr[j] * ad3[h * O3 + j];
        }
        acc += __shfl_xor(acc, 1);
        acc += __shfl_xor(acc, 2);
        acc += __shfl_xor(acc, 4);
        if (sub == 0) W3b[oid] = f2bf(acc);
    }
    if (i < NCLS * 8) {      // btv[c] = sum_k (sum_h b3[h,k]) * wp[k,c]
        int c = i >> 3, sub = i & 7;
        float acc = 0.f;
        for (int k = sub; k < O3; k += 8) {
            float bs = 0.f;
            #pragma unroll
            for (int hh = 0; hh < H3; hh++) bs += b3[hh * O3 + k];
            acc += bs * wp[k * NCLS + c];
        }
        acc += __shfl_xor(acc, 1);
        acc += __shfl_xor(acc, 2);
        acc += __shfl_xor(acc, 4);
        if (sub == 0) btv[c] = acc;
    }
}

// ---------------- MFMA GEMM: C[MxN] = A[MxK] * BT[NxK]^T ----------------
// SPLIT=true : split-bf16 A and B (3 MFMA per frag) — conv1 only.
// MODE 0: bf16 P out (N=256) + fused es/ed logits epilogue (as_/ad_ [4][64]).
// MODE 1: bf16 Q[.,60] + fp32 es[.,6] + ed[.,6] (conv3 pre-folded B).

template <int MODE, bool SPLIT>
__global__ __launch_bounds__(256) void gemm_mfma_kernel(
    const unsigned short* __restrict__ Ahi, const unsigned short* __restrict__ Alo,
    const unsigned short* __restrict__ Bhi, const unsigned short* __restrict__ Blo,
    unsigned short* __restrict__ Cbf, unsigned short* __restrict__ Qb,
    float* __restrict__ es, float* __restrict__ ed,
    const float* __restrict__ as_, const float* __restrict__ ad_,
    int M, int K, int N) {
    __shared__ unsigned short sAh[128 * LDA], sBh[128 * LDA];
    __shared__ unsigned short sAl[SPLIT ? 128 * LDA : 1], sBl[SPLIT ? 128 * LDA : 1];
    int tid = threadIdx.x;
    int lane = tid & 63, wave = tid >> 6;
    int wr = (wave >> 1) * 64, wc = (wave & 1) * 64;
    int quad = lane >> 4, mr = lane & 15;
    int row0 = blockIdx.y * 128, col0 = blockIdx.x * 128;

    floatx4 zero = {0.f, 0.f, 0.f, 0.f};
    floatx4 acc[4][4];
    #pragma unroll
    for (int i = 0; i < 4; i++)
        #pragma unroll
        for (int j = 0; j < 4; j++) acc[i][j] = zero;

    for (int k0 = 0; k0 < K; k0 += 32) {
        #pragma unroll
        for (int ch = 0; ch < 2; ch++) {
            int linear = (ch * 256 + tid) * 8;   // 128*32 = 4096 elements
            int r = linear >> 5, c = linear & 31;
            uint4 vh, vl;
            int gr = row0 + r;
            if (gr < M) {
                vh = *(const uint4*)(Ahi + (size_t)gr * K + k0 + c);
                if (SPLIT) vl = *(const uint4*)(Alo + (size_t)gr * K + k0 + c);
            } else { vh = uint4{0, 0, 0, 0}; vl = uint4{0, 0, 0, 0}; }
            *(uint4*)&sAh[r * LDA + c] = vh;
            if (SPLIT) *(uint4*)&sAl[r * LDA + c] = vl;
            int gn = col0 + r;
            if (gn < N) {
                vh = *(const uint4*)(Bhi + (size_t)gn * K + k0 + c);
                if (SPLIT) vl = *(const uint4*)(Blo + (size_t)gn * K + k0 + c);
            } else { vh = uint4{0, 0, 0, 0}; vl = uint4{0, 0, 0, 0}; }
            *(uint4*)&sBh[r * LDA + c] = vh;
            if (SPLIT) *(uint4*)&sBl[r * LDA + c] = vl;
        }
        __syncthreads();

        short8 ah[4], al[4], bh[4], bl[4];
        #pragma unroll
        for (int i = 0; i < 4; i++) {
            int ar = wr + i * 16 + mr;
            ah[i] = *(const short8*)&sAh[ar * LDA + quad * 8];
            if (SPLIT) al[i] = *(const short8*)&sAl[ar * LDA + quad * 8];
            int br = wc + i * 16 + mr;
            bh[i] = *(const short8*)&sBh[br * LDA + quad * 8];
            if (SPLIT) bl[i] = *(const short8*)&sBl[br * LDA + quad * 8];
        }
        #pragma unroll
        for (int i = 0; i < 4; i++)
            #pragma unroll
            for (int j = 0; j < 4; j++) {
                acc[i][j] = __builtin_amdgcn_mfma_f32_16x16x32_bf16(ah[i], bh[j], acc[i][j], 0, 0, 0);
                if (SPLIT) {
                    acc[i][j] = __builtin_amdgcn_mfma_f32_16x16x32_bf16(ah[i], bl[j], acc[i][j], 0, 0, 0);
                    acc[i][j] = __builtin_amdgcn_mfma_f32_16x16x32_bf16(al[i], bh[j], acc[i][j], 0, 0, 0);
                }
            }
        __syncthreads();
    }

    #pragma unroll
    for (int i = 0; i < 4; i++) {
        #pragma unroll
        for (int j = 0; j < 4; j++) {
            int gc = col0 + wc + j * 16 + mr;
            if (gc >= N) continue;
            int gr0 = row0 + wr + i * 16 + quad * 4;
            #pragma unroll
            for (int r = 0; r < 4; r++) {
                int gr = gr0 + r;
                if (gr >= M) continue;
                float v = acc[i][j][r];
                if (MODE == 0) {
                    Cbf[(size_t)gr * D1 + gc] = f2bf(v);
                } else {
                    if (gc < NQ)            Qb[(size_t)gr * NQ + gc] = f2bf(v);
                    else if (gc < NQ + H3)  es[(size_t)gr * H3 + (gc - NQ)] = v;
                    else                    ed[(size_t)gr * H3 + (gc - NQ - H3)] = v;
                }
            }
        }
    }

    if (MODE == 0) {
        // fused logits: this wave owns head hx for rows wr..wr+63
        int hx = 2 * blockIdx.x + (wave & 1);
        float asr[4], adr[4];
        #pragma unroll
        for (int j = 0; j < 4; j++) {
            asr[j] = as_[hx * 64 + j * 16 + mr];
            adr[j] = ad_[hx * 64 + j * 16 + mr];
        }
        #pragma unroll
        for (int i = 0; i < 4; i++) {
            #pragma unroll
            for (int r = 0; r < 4; r++) {
                float ps = 0.f, pd = 0.f;
                #pragma unroll
                for (int j = 0; j < 4; j++) {
                    float v = acc[i][j][r];
                    ps += v * asr[j];
                    pd += v * adr[j];
                }
                #pragma unroll
                for (int m2 = 8; m2 >= 1; m2 >>= 1) {
                    ps += __shfl_xor(ps, m2);
                    pd += __shfl_xor(pd, m2);
                }
                int gr = row0 + wr + i * 16 + quad * 4 + r;
                if (mr == 0 && gr < M) {
                    es[gr * 4 + hx] = ps;
                    ed[gr * 4 + hx] = pd;
                }
            }
        }
    }
}

// ---------------- conv1/2: one-pass softmax aggregation ----------------
// Half-wave per edge: lanes 0-31 even edge, 32-63 odd edge; 8 features/lane
// (ushort8 = 16B loads). shfl_xor(32) merges the two half-softmax partials.

__global__ __launch_bounds__(256) void aggregate12_kernel(
    const unsigned short* __restrict__ P, const float* __restrict__ es,
    const float* __restrict__ ed, const int* __restrict__ cnt,
    const int* __restrict__ csr, const float* __restrict__ bias,
    unsigned short* __restrict__ outHi) {
    int wave = threadIdx.x >> 6, lane = threadIdx.x & 63;
    int wid = blockIdx.x * 4 + wave;
    int hi = lane >> 5;            // which edge of the pair
    int fl = lane & 31;            // feature-lane: features fl*8 .. fl*8+7
    int hq = fl >> 3;              // head of those features
    int f0 = fl * 8;
    float bv[8];
    #pragma unroll
    for (int j = 0; j < 8; j++) bv[j] = bias[f0 + j];
    #pragma unroll 1
    for (int t = 0; t < 4; t++) {
        int dst = wid * 4 + t;
        int s0 = dst * CAP, s1 = s0 + cnt[dst];
        float edv = ed[dst * 4 + hq];
        float sum = 0.f;
        float acc[8];
        #pragma unroll
        for (int j = 0; j < 8; j++) acc[j] = 0.f;
        int s = s0;
        for (; s + 8 <= s1; s += 8) {      // 4 pairs = 8 edges
            int si[4]; float ev[4]; ushort8 pp[4];
            #pragma unroll
            for (int u = 0; u < 4; u++) si[u] = csr[s + 2 * u + hi];
            #pragma unroll
            for (int u = 0; u < 4; u++) {
                ev[u] = es[si[u] * 4 + hq] + edv;
                pp[u] = *(const ushort8*)(P + (size_t)si[u] * D1 + f0);
            }
            #pragma unroll
            for (int u = 0; u < 4; u++) {
                float e = __expf(lrelu(ev[u]));
                sum += e;
                #pragma unroll
                for (int j = 0; j < 8; j++) acc[j] += e * bf2f(pp[u][j]);
            }
        }
        for (; s + 4 <= s1; s += 4) {      // 2 pairs = 4 edges
            int si[2]; float ev[2]; ushort8 pp[2];
            #pragma unroll
            for (int u = 0; u < 2; u++) si[u] = csr[s + 2 * u + hi];
            #pragma unroll
            for (int u = 0; u < 2; u++) {
                ev[u] = es[si[u] * 4 + hq] + edv;
                pp[u] = *(const ushort8*)(P + (size_t)si[u] * D1 + f0);
            }
            #pragma unroll
            for (int u = 0; u < 2; u++) {
                float e = __expf(lrelu(ev[u]));
                sum += e;
                #pragma unroll
                for (int j = 0; j < 8; j++) acc[j] += e * bf2f(pp[u][j]);
            }
        }
        for (; s < s1; s += 2) {           // masked final pair (1-2 edges)
            int idx = s + hi;
            bool v = idx < s1;
            int si = csr[v ? idx : s];
            float evv = es[si * 4 + hq] + edv;
            ushort8 p8 = *(const ushort8*)(P + (size_t)si * D1 + f0);
            float e = v ? __expf(lrelu(evv)) : 0.f;
            sum += e;
            #pragma unroll
            for (int j = 0; j < 8; j++) acc[j] += e * bf2f(p8[j]);
        }
        sum += __shfl_xor(sum, 32);
        #pragma unroll
        for (int j = 0; j < 8; j++) acc[j] += __shfl_xor(acc[j], 32);
        float inv = 1.f / sum;
        if (lane < 32) {
            ushort8 o8;
            #pragma unroll
            for (int j = 0; j < 8; j++) {
                float a = acc[j] * inv + bv[j];
                a = a > 0.f ? a : expm1f(a);
                o8[j] = f2bf(a);
            }
            *(ushort8*)(outHi + (size_t)dst * D1 + f0) = o8;
        }
    }
}

// ---------------- conv3: one-pass softmax + Q-gather + pool + fused classifier ----

__global__ __launch_bounds__(256) void aggregate3q_kernel(
    const unsigned short* __restrict__ Qb, const float* __restrict__ es,
    const float* __restrict__ ed, const int* __restrict__ cnt,
    const int* __restrict__ csr, const int* __restrict__ batch,
    float* __restrict__ G,
    const int* __restrict__ gs, const int* __restrict__ ge,
    const float* __restrict__ btv, const float* __restrict__ bp,
    float* __restrict__ out, int* __restrict__ bar) {
    __shared__ int s_last;
    int wave = threadIdx.x >> 6, lane = threadIdx.x & 63;
    int wid = blockIdx.x * 4 + wave;
    bool act = lane < NQ;
    int h = act ? (lane / NCLS) : 0;
    int q = act ? lane : 0;
    #pragma unroll 1
    for (int t = 0; t < 4; t++) {
        int dst = wid * 4 + t;
        int b = batch[dst];
        int s0 = dst * CAP, s1 = s0 + cnt[dst];
        float edv = act ? ed[dst * H3 + h] : 0.f;
        float sum = 0.f, acc = 0.f;
        int s = s0;
        for (; s + 8 <= s1; s += 8) {
            int si[8];
            #pragma unroll
            for (int u = 0; u < 8; u++) si[u] = csr[s + u];
            float vv[8], qq[8];
            #pragma unroll
            for (int u = 0; u < 8; u++) {
                vv[u] = es[si[u] * H3 + h] + edv;
                qq[u] = bf2f(Qb[(size_t)si[u] * NQ + q]);
            }
            #pragma unroll
            for (int u = 0; u < 8; u++) {
                float e = __expf(lrelu(vv[u]));
                sum += e;
                acc += e * qq[u];
            }
        }
        for (; s + 2 <= s1; s += 2) {
            int sa = csr[s], sb = csr[s + 1];
            float va = es[sa * H3 + h] + edv;
            float vb = es[sb * H3 + h] + edv;
            float qa = bf2f(Qb[(size_t)sa * NQ + q]);
            float qb = bf2f(Qb[(size_t)sb * NQ + q]);
            float ea = __expf(lrelu(va));
            float eb = __expf(lrelu(vb));
            sum += ea + eb;
            acc += ea * qa + eb * qb;
        }
        for (; s < s1; s++) {
            int sa = csr[s];
            float va = es[sa * H3 + h] + edv;
            float qa = bf2f(Qb[(size_t)sa * NQ + q]);
            float ea = __expf(lrelu(va));
            sum += ea;
            acc += ea * qa;
        }
        acc *= 1.f / sum;
        float av = act ? acc : 0.f;
        float tot = av;
        #pragma unroll
        for (int h2 = 1; h2 < H3; h2++) tot += __shfl(av, lane + h2 * NCLS);
        if (lane < NCLS) atomicAdd(&G[b * NCLS + lane], tot);
    }

    // fused final classifier: last block to finish does the [NB,NCLS] epilogue.
    // Release ordering: each wave drains its device-scope G atomics via
    // s_waitcnt vmcnt(0) (cheap; no L2-writeback cache op) before the barrier.
    // Device-scope atomics complete at the device coherence point, so completed
    // == globally visible. Acquire: ONE threadfence in the single last block
    // (L2 invalidate) before plain reads of G. (R4's per-block __threadfence
    // cost ~20us across 1875 blocks.)
    asm volatile("s_waitcnt vmcnt(0)" ::: "memory");
    __syncthreads();
    if (threadIdx.x == 0) {
        int old = atomicAdd(bar, 1);
        int last = (old == (int)gridDim.x - 1) ? 1 : 0;
        if (last) __threadfence();   // acquire: G atomics from all blocks visible
        s_last = last;
    }
    __syncthreads();
    if (s_last) {
        for (int i = threadIdx.x; i < NB * NCLS; i += blockDim.x) {
            int b = i / NCLS, c = i % NCLS;
            int cntn = ge[b] - gs[b];
            float o = bp[c];
            if (cntn > 0)
                o += G[i] / (6.f * (float)cntn) + btv[c] * (1.f / 6.f);
            out[i] = o;
        }
    }
}

// ---------------- launch ----------------

extern "C" void kernel_launch(void* const* d_in, const int* in_sizes, int n_in,
                              void* d_out, int out_size, void* d_ws, size_t ws_size,
                              hipStream_t stream) {
    const int* x     = (const int*)d_in[0];
    const int* dep   = (const int*)d_in[1];
    const int* ei    = (const int*)d_in[2];
    const int* batch = (const int*)d_in[3];
    const float* nemb = (const float*)d_in[4];
    const float* demb = (const float*)d_in[5];
    const float* w1  = (const float*)d_in[6];
    const float* as1 = (const float*)d_in[7];
    const float* ad1 = (const float*)d_in[8];
    const float* b1  = (const float*)d_in[9];
    const float* w2  = (const float*)d_in[10];
    const float* as2 = (const float*)d_in[11];
    const float* ad2 = (const float*)d_in[12];
    const float* b2  = (const float*)d_in[13];
    const float* w3  = (const float*)d_in[14];
    const float* as3 = (const float*)d_in[15];
    const float* ad3 = (const float*)d_in[16];
    const float* b3  = (const float*)d_in[17];
    const float* wp  = (const float*)d_in[18];
    const float* bp  = (const float*)d_in[19];
    float* out = (float*)d_out;

    char* ws = (char*)d_ws;
    size_t off = 0;
    auto alloc = [&](size_t bytes) -> void* {
        void* p = ws + off;
        off += (bytes + 255) & ~(size_t)255;
        return p;
    };
    unsigned short* Hb   = (unsigned short*)alloc((size_t)NN * D1 * 2);     // H0 (stride 64) then H1/H2 (stride 256)
    unsigned short* H0lo = (unsigned short*)alloc((size_t)NN * EMB * 2);    // H0 lo (conv1 split A)
    unsigned short* W1hi = (unsigned short*)alloc((size_t)D1 * EMB * 2);
    unsigned short* W1lo = (unsigned short*)alloc((size_t)D1 * EMB * 2);
    unsigned short* W2b  = (unsigned short*)alloc((size_t)D1 * D1 * 2);
    unsigned short* W3b  = (unsigned short*)alloc((size_t)N3 * D1 * 2);
    unsigned short* Pb   = (unsigned short*)alloc((size_t)NN * D1 * 2);     // bf16 P (conv1/2)
    unsigned short* Qb   = (unsigned short*)alloc(((size_t)NN * NQ + 64) * 2);
    float* es   = (float*)alloc((size_t)NN * 6 * 4);
    float* ed   = (float*)alloc((size_t)NN * 6 * 4);
    int* csr    = (int*)alloc((size_t)NN * CAP * 4);                        // padded CSR
    float* btv  = (float*)alloc((size_t)NCLS * 4);
    // ---- contiguous zero-region (one hipMemsetAsync covers all of it) ----
    char* zstart = ws + off;
    float* G    = (float*)alloc((size_t)NB * NCLS * 4);
    int* gs     = (int*)alloc((size_t)NB * 4);
    int* ge     = (int*)alloc((size_t)NB * 4);
    int* cnt    = (int*)alloc((size_t)NN * 4);
    int* bar    = (int*)alloc((size_t)64 * 4);
    size_t zbytes = (size_t)((ws + off) - zstart);

    hipMemsetAsync(zstart, 0, zbytes, stream);

    // --- fused preprocessing (1 kernel) ---
    setup_kernel<<<ceil_div(NN * EMB, 256), 256, 0, stream>>>(
        x, dep, ei, batch, nemb, demb, w1, w2, w3, as3, ad3, wp, b3,
        Hb, H0lo, W1hi, W1lo, W2b, W3b, btv, cnt, csr, gs, ge);

    // --- conv1: [NN,64] -> [NN,256] split-bf16 GEMM, logits fused ---
    gemm_mfma_kernel<0, true><<<dim3(2, ceil_div(NN, 128)), 256, 0, stream>>>(
        Hb, H0lo, W1hi, W1lo, Pb, nullptr, es, ed, as1, ad1, NN, EMB, D1);
    aggregate12_kernel<<<NN / 16, 256, 0, stream>>>(Pb, es, ed, cnt, csr, b1, Hb);

    // --- conv2: [NN,256] -> [NN,256] plain bf16 GEMM, logits fused ---
    gemm_mfma_kernel<0, false><<<dim3(2, ceil_div(NN, 128)), 256, 0, stream>>>(
        Hb, nullptr, W2b, nullptr, Pb, nullptr, es, ed, as2, ad2, NN, D1, D1);
    aggregate12_kernel<<<NN / 16, 256, 0, stream>>>(Pb, es, ed, cnt, csr, b2, Hb);

    // --- conv3 folded: [NN,256] -> Qb[NN,60](bf16) + es/ed[NN,6] ---
    gemm_mfma_kernel<1, false><<<dim3(1, ceil_div(NN, 128)), 256, 0, stream>>>(
        Hb, nullptr, W3b, nullptr, nullptr, Qb, es, ed, nullptr, nullptr, NN, D1, N3);

    // --- conv3 aggregation + pool + fused final classifier (last-block) ---
    aggregate3q_kernel<<<NN / 16, 256, 0, stream>>>(
        Qb, es, ed, cnt, csr, batch, G, gs, ge, btv, bp, out, bar);
}